// Round 3
// baseline (12203.004 us; speedup 1.0000x reference)
//
#include <hip/hip_runtime.h>

typedef __attribute__((ext_vector_type(8))) short bf16x8;
typedef __attribute__((ext_vector_type(4))) float f32x4;

__device__ __forceinline__ float bf2f(unsigned short u) {
  union { float f; unsigned int i; } v; v.i = ((unsigned int)u) << 16; return v.f;
}
__device__ __forceinline__ unsigned short f2bf(float f) {
  union { float f; unsigned int i; } v; v.f = f;
  unsigned int r = v.i + 0x7fffu + ((v.i >> 16) & 1u);
  return (unsigned short)(r >> 16);
}
__device__ __forceinline__ float sigf(float x) { return 1.0f / (1.0f + expf(-x)); }
__device__ __forceinline__ float softplusf(float x) {
  return (x > 20.0f) ? x : log1pf(expf(x));
}
// NaN firewall: fmaxf(NaN, -1e6) = -1e6 (IEEE maxNum) => output provably finite
__device__ __forceinline__ float sat(float v) {
  return fminf(fmaxf(v, -1.0e6f), 1.0e6f);
}
__device__ __forceinline__ float ldx(const void* p, int is32, long i) {
  return is32 ? ((const float*)p)[i] : bf2f(((const unsigned short*)p)[i]);
}
__device__ __forceinline__ bf16x8 load8(const void* base, long off, int is32) {
  if (is32) {
    const float* p = (const float*)base + off;
    f32x4 a = *(const f32x4*)p;
    f32x4 b = *(const f32x4*)(p + 4);
    bf16x8 r;
    r[0] = (short)f2bf(a[0]); r[1] = (short)f2bf(a[1]);
    r[2] = (short)f2bf(a[2]); r[3] = (short)f2bf(a[3]);
    r[4] = (short)f2bf(b[0]); r[5] = (short)f2bf(b[1]);
    r[6] = (short)f2bf(b[2]); r[7] = (short)f2bf(b[3]);
    return r;
  }
  return *(const bf16x8*)((const unsigned short*)base + off);
}

// flags[0] = C/D layout swap (from probe_layout), flags[1] = dtype (0=bf16,1=fp32)

__global__ __launch_bounds__(64) void probe_dtype(
    const unsigned int* __restrict__ w, int* __restrict__ flags)
{
  const int lane = threadIdx.x;
  int cnt = 0;
  for (int i = 0; i < 16; ++i) {
    unsigned int word = w[lane * 16 + i];
    float av = fabsf(bf2f((unsigned short)(word & 0xFFFFu)));
    if (av > 1.0e-4f && av < 1.0f) cnt++;
  }
  #pragma unroll
  for (int off = 32; off > 0; off >>= 1) cnt += __shfl_xor(cnt, off);
  if (lane == 0) flags[1] = (cnt > 512) ? 0 : 1;
}

__global__ __launch_bounds__(64) void probe_layout(int* __restrict__ flags) {
  const int lane = threadIdx.x;
  const int qr = lane & 15, quad = lane >> 4;
  bf16x8 a, b;
  #pragma unroll
  for (int j = 0; j < 8; ++j) {
    int k = quad * 8 + j;
    a[j] = (short)f2bf((k == qr) ? 1.0f : 0.0f);
    b[j] = (short)f2bf((float)(k + 1));
  }
  f32x4 acc = {0.0f, 0.0f, 0.0f, 0.0f};
  acc = __builtin_amdgcn_mfma_f32_16x16x32_bf16(a, b, acc, 0, 0, 0);
  bool ok0 = true, ok1 = true;
  #pragma unroll
  for (int rg = 0; rg < 4; ++rg) {
    ok0 = ok0 && (acc[rg] == (float)(quad * 4 + rg + 1));
    ok1 = ok1 && (acc[rg] == (float)(qr + 1));
  }
  int a0 = __all(ok0 ? 1 : 0);
  int a1 = __all(ok1 ? 1 : 0);
  if (lane == 0) flags[0] = a0 ? 0 : (a1 ? 1 : 0);
}

// C[M,N] = A[M,K]*B[N,K]^T. aMode/bMode: 0=bf16, 1=follow flag, 2=fp32.
// EPI 0: fp32 C store (ACC accumulates). EPI 1: sat(v)+bias -> Cbf + outOff
// (bf16, or fp32 if outFollow&&flag). EPI 2: split-K fp32 partial -> C.
template<int BM, int BN, int EPI, int ACC>
__global__ __launch_bounds__(256) void gemm_bt(
    const void* __restrict__ A, int lda,
    const void* __restrict__ B, int ldb,
    int M, int N, int K, int kChunk,
    float* __restrict__ C, long long ldc,
    const void* __restrict__ bias, void* __restrict__ Cbf, long long outOff,
    const int* __restrict__ flags,
    int aMode, int bMode, int biasFollow, int outFollow)
{
  constexpr int BK = 64;
  constexpr int LDT = BK + 8;
  __shared__ unsigned short As[BM][LDT];
  __shared__ unsigned short Bs[BN][LDT];
  const int tid = threadIdx.x;
  const int lane = tid & 63, wid = tid >> 6;
  const int wm = wid & 1, wn = wid >> 1;
  constexpr int WM = BM / 2, WN = BN / 2;
  constexpr int TM = WM / 16, TN = WN / 16;
  const int m0 = blockIdx.x * BM, n0 = blockIdx.y * BN;
  const int kBeg = blockIdx.z * kChunk;
  int kEnd = kBeg + kChunk; if (kEnd > K) kEnd = K;
  const int qr = lane & 15, quad = lane >> 4;
  const int F = flags[1];
  const int a32 = (aMode == 2) || (aMode == 1 && F);
  const int b32 = (bMode == 2) || (bMode == 1 && F);

  f32x4 acc[TM][TN];
  #pragma unroll
  for (int mt = 0; mt < TM; ++mt)
    #pragma unroll
    for (int nt = 0; nt < TN; ++nt)
      #pragma unroll
      for (int rg = 0; rg < 4; ++rg) acc[mt][nt][rg] = 0.0f;

  for (int k0 = kBeg; k0 < kEnd; k0 += BK) {
    #pragma unroll
    for (int i = 0; i < BM / 32; ++i) {
      int linear = i * 256 + tid;
      int row = linear >> 3, q = (linear & 7) << 3;
      int gm = m0 + row;
      bf16x8 v = {0,0,0,0,0,0,0,0};
      if (gm < M) v = load8(A, (long)gm * lda + k0 + q, a32);
      *(bf16x8*)&As[row][q] = v;
    }
    #pragma unroll
    for (int i = 0; i < BN / 32; ++i) {
      int linear = i * 256 + tid;
      int row = linear >> 3, q = (linear & 7) << 3;
      int gn = n0 + row;
      bf16x8 v = {0,0,0,0,0,0,0,0};
      if (gn < N) v = load8(B, (long)gn * ldb + k0 + q, b32);
      *(bf16x8*)&Bs[row][q] = v;
    }
    __syncthreads();
    #pragma unroll
    for (int ks = 0; ks < BK; ks += 32) {
      bf16x8 af[TM], bfr[TN];
      #pragma unroll
      for (int mt = 0; mt < TM; ++mt)
        af[mt] = *(const bf16x8*)&As[wm * WM + mt * 16 + qr][ks + quad * 8];
      #pragma unroll
      for (int nt = 0; nt < TN; ++nt)
        bfr[nt] = *(const bf16x8*)&Bs[wn * WN + nt * 16 + qr][ks + quad * 8];
      #pragma unroll
      for (int mt = 0; mt < TM; ++mt)
        #pragma unroll
        for (int nt = 0; nt < TN; ++nt)
          acc[mt][nt] = __builtin_amdgcn_mfma_f32_16x16x32_bf16(af[mt], bfr[nt], acc[mt][nt], 0, 0, 0);
    }
    __syncthreads();
  }

  const int swap = flags[0];
  const int o32 = outFollow && F;
  const int bias32 = biasFollow && F;
  #pragma unroll
  for (int mt = 0; mt < TM; ++mt) {
    #pragma unroll
    for (int nt = 0; nt < TN; ++nt) {
      #pragma unroll
      for (int rg = 0; rg < 4; ++rg) {
        int ri = swap ? qr : (quad * 4 + rg);
        int ci = swap ? (quad * 4 + rg) : qr;
        int gm = m0 + wm * WM + mt * 16 + ri;
        int gn = n0 + wn * WN + nt * 16 + ci;
        float v = acc[mt][nt][rg];
        if (EPI == 0) {
          if (gm < M && gn < N) {
            size_t idx = (size_t)gm * ldc + gn;
            if (ACC) v += C[idx];
            C[idx] = sat(v);
          }
        } else if (EPI == 1) {
          if (gm < M && gn < N) {
            float bv = bias ? ldx(bias, bias32, gn) : 0.0f;
            float vv = sat(v + bv);
            size_t idx = (size_t)(outOff + (long long)gm * ldc + gn);
            if (o32) ((float*)Cbf)[idx] = vv;
            else ((unsigned short*)Cbf)[idx] = f2bf(vv);
          }
        } else {
          C[(size_t)blockIdx.z * M * N + (size_t)gm * N + gn] = sat(v);
        }
      }
    }
  }
}

__global__ __launch_bounds__(256) void lstm_ew(
    const float* __restrict__ Cg, const void* __restrict__ bih,
    const void* __restrict__ bhh, float* __restrict__ c,
    unsigned short* __restrict__ ci_h, const void* __restrict__ x, int t,
    const int* __restrict__ flags)
{
  const int F = flags[1];
  const int bx = blockIdx.x;
  if (bx < 512) {
    int idx = bx * 256 + threadIdx.x;          // 128*1024
    int b = idx >> 10, j = idx & 1023;
    const float* g = Cg + (size_t)b * 4096;
    float iv = g[j]        + ldx(bih, F, j)        + ldx(bhh, F, j);
    float fv = g[1024 + j] + ldx(bih, F, 1024 + j) + ldx(bhh, F, 1024 + j);
    float gv = g[2048 + j] + ldx(bih, F, 2048 + j) + ldx(bhh, F, 2048 + j);
    float ov = g[3072 + j] + ldx(bih, F, 3072 + j) + ldx(bhh, F, 3072 + j);
    float cn = sat(sigf(fv) * c[idx] + sigf(iv) * tanhf(gv));
    c[idx] = cn;
    float h = sigf(ov) * tanhf(cn);
    ci_h[b * 1664 + 640 + j] = f2bf(h);
  } else if (t + 1 < 32) {
    int e = (bx - 512) * 256 + threadIdx.x;    // 128*512
    int b = e >> 9, k = e & 511;
    ci_h[b * 1664 + k] = f2bf(ldx(x, F, (long)b * 16384 + (long)(t + 1) * 512 + k));
  }
}

__global__ __launch_bounds__(128) void heads_post_keys(
    const float* __restrict__ Hout, const void* __restrict__ rkb,
    const void* __restrict__ wkb, unsigned short* __restrict__ keys_n,
    const int* __restrict__ flags)
{
  const int F = flags[1];
  const int id = blockIdx.x;
  const int x = id >> 7, b = id & 127;
  const int w = threadIdx.x;
  float v = Hout[(size_t)(x * 128 + w) * 128 + b] + ldx(x ? wkb : rkb, F, w);
  __shared__ float s2[2];
  float p = v * v;
  #pragma unroll
  for (int off = 32; off > 0; off >>= 1) p += __shfl_xor(p, off);
  if ((w & 63) == 0) s2[w >> 6] = p;
  __syncthreads();
  float inv = 1.0f / fmaxf(sqrtf(s2[0] + s2[1]), 1e-12f);
  keys_n[(size_t)id * 128 + w] = f2bf(v * inv);
}

__global__ __launch_bounds__(256) void heads_post_ea(
    const float* __restrict__ Hout, const void* __restrict__ erb,
    const void* __restrict__ adb, unsigned short* __restrict__ EA,
    const int* __restrict__ flags)
{
  const int F = flags[1];
  int idx = blockIdx.x * 256 + threadIdx.x;   // 32768
  int j = idx >> 7;
  bool isEr = j < 128;
  int w = isEr ? j : j - 128;
  float v = Hout[(size_t)(256 + j) * 128 + (idx & 127)] + ldx(isEr ? erb : adb, F, w);
  v = isEr ? sigf(v) : tanhf(v);
  EA[idx] = f2bf(v);
}

__global__ __launch_bounds__(256) void scalar_heads(
    const unsigned short* __restrict__ Wsc, const unsigned short* __restrict__ co_bf,
    const void* __restrict__ rbb, const void* __restrict__ rgb,
    const void* __restrict__ wbb, const void* __restrict__ wgb,
    float* __restrict__ sc, const int* __restrict__ flags)
{
  const int F = flags[1];
  const int tid = threadIdx.x;
  const int lane = tid & 63, h = tid >> 6;
  const int n0 = blockIdx.x * 64;
  float wv[15];
  #pragma unroll
  for (int i = 0; i < 15; ++i) wv[i] = bf2f(Wsc[h * 960 + i * 64 + lane]);
  const void* bptr = (h == 0) ? rbb : (h == 1) ? rgb : (h == 2) ? wbb : wgb;
  const float bias_h = ldx(bptr, F, 0);
  for (int bb = 0; bb < 64; ++bb) {
    int b = n0 + bb;
    float s = 0.0f;
    #pragma unroll
    for (int i = 0; i < 15; ++i) s += wv[i] * bf2f(co_bf[b * 960 + i * 64 + lane]);
    #pragma unroll
    for (int off = 32; off > 0; off >>= 1) s += __shfl_down(s, off);
    if (lane == 0) {
      float sp = fminf(softplusf(sat(s + bias_h)), 1.0e4f);
      sc[h * 128 + b] = (h & 1) ? (1.0f + sp) : sp;
    }
  }
}

__global__ __launch_bounds__(256) void softmax_interp(
    const unsigned short* __restrict__ Csim, const float* __restrict__ sc,
    float* __restrict__ rw, unsigned short* __restrict__ ww_nat)
{
  const int r = blockIdx.x, tid = threadIdx.x;
  const int b = r & 127;
  const bool isRead = r < 128;
  const float beta  = isRead ? sc[b]       : sc[256 + b];
  const float gamma = isRead ? sc[128 + b] : sc[384 + b];
  const unsigned short* row = Csim + (size_t)r * 16384;
  __shared__ float red[4];
  float mx = -3.0e38f;
  for (int i = tid; i < 16384; i += 256) mx = fmaxf(mx, bf2f(row[i]));
  #pragma unroll
  for (int off = 32; off > 0; off >>= 1) mx = fmaxf(mx, __shfl_xor(mx, off));
  if ((tid & 63) == 0) red[tid >> 6] = mx;
  __syncthreads();
  mx = fmaxf(fmaxf(red[0], red[1]), fmaxf(red[2], red[3]));
  const float m = beta * mx;
  __syncthreads();
  float s = 0.0f;
  for (int i = tid; i < 16384; i += 256) s += expf(beta * bf2f(row[i]) - m);
  #pragma unroll
  for (int off = 32; off > 0; off >>= 1) s += __shfl_xor(s, off);
  if ((tid & 63) == 0) red[tid >> 6] = s;
  __syncthreads();
  s = red[0] + red[1] + red[2] + red[3];
  const float inv = 1.0f / fmaxf(s, 1e-30f);
  if (isRead) {
    float* prow = rw + (size_t)b * 16384;
    for (int i = tid; i < 16384; i += 256) {
      float p = expf(beta * bf2f(row[i]) - m) * inv;
      prow[i] = sat(gamma * p + (1.0f - gamma) * prow[i]);
    }
  } else {
    unsigned short* wrow = ww_nat + (size_t)b * 16384;
    const float u = 1.0f / 16384.0f;
    for (int i = tid; i < 16384; i += 256) {
      float p = expf(beta * bf2f(row[i]) - m) * inv;
      wrow[i] = f2bf(sat(gamma * p + (1.0f - gamma) * u));
    }
  }
}

__global__ __launch_bounds__(256) void transpose_ww(
    const unsigned short* __restrict__ src, unsigned short* __restrict__ dst)
{
  __shared__ unsigned short tile[64][65];
  const int n0 = blockIdx.x * 64, b0 = blockIdx.y * 64;
  for (int e = threadIdx.x; e < 4096; e += 256) {
    int rb = e >> 6, cn = e & 63;
    tile[rb][cn] = src[(size_t)(b0 + rb) * 16384 + n0 + cn];
  }
  __syncthreads();
  for (int e = threadIdx.x; e < 4096; e += 256) {
    int rn = e >> 6, cb = e & 63;
    dst[(size_t)(n0 + rn) * 128 + b0 + cb] = tile[cb][rn];
  }
}

__global__ __launch_bounds__(256) void mem_update(
    const unsigned short* __restrict__ Cea, float* __restrict__ mem,
    unsigned short* __restrict__ memn, unsigned short* __restrict__ mem_t)
{
  __shared__ float tile[64][129];
  __shared__ float inv[64];
  const int n0 = blockIdx.x * 64, tid = threadIdx.x;
  for (int e = tid; e < 8192; e += 256) {
    int r = e >> 7, w = e & 127;
    size_t gi = (size_t)(n0 + r) * 128 + w;
    float er = bf2f(Cea[(size_t)(n0 + r) * 256 + w]);
    float ad = bf2f(Cea[(size_t)(n0 + r) * 256 + 128 + w]);
    float nv = sat(mem[gi] * (1.0f - er) + ad);
    mem[gi] = nv;
    tile[r][w] = nv;
  }
  __syncthreads();
  if (tid < 64) {
    float ss = 0.0f;
    for (int w = 0; w < 128; ++w) { float v = tile[tid][w]; ss += v * v; }
    inv[tid] = 1.0f / fmaxf(sqrtf(ss), 1e-12f);
  }
  __syncthreads();
  for (int e = tid; e < 8192; e += 256) {
    int r = e >> 7, w = e & 127;
    memn[(size_t)(n0 + r) * 128 + w] = f2bf(tile[r][w] * inv[r]);
  }
  for (int e = tid; e < 8192; e += 256) {
    int w = e >> 6, r = e & 63;
    mem_t[(size_t)w * 16384 + n0 + r] = f2bf(tile[r][w]);
  }
}

__global__ __launch_bounds__(256) void init_mem(
    const void* __restrict__ memory, float* __restrict__ mem,
    unsigned short* __restrict__ memn, unsigned short* __restrict__ mem_t,
    const int* __restrict__ flags)
{
  const int F = flags[1];
  __shared__ float tile[64][129];
  __shared__ float inv[64];
  const int n0 = blockIdx.x * 64, tid = threadIdx.x;
  for (int e = tid; e < 8192; e += 256) {
    int r = e >> 7, w = e & 127;
    size_t gi = (size_t)(n0 + r) * 128 + w;
    float nv = ldx(memory, F, (long)gi);
    mem[gi] = nv;
    tile[r][w] = nv;
  }
  __syncthreads();
  if (tid < 64) {
    float ss = 0.0f;
    for (int w = 0; w < 128; ++w) { float v = tile[tid][w]; ss += v * v; }
    inv[tid] = 1.0f / fmaxf(sqrtf(ss), 1e-12f);
  }
  __syncthreads();
  for (int e = tid; e < 8192; e += 256) {
    int r = e >> 7, w = e & 127;
    memn[(size_t)(n0 + r) * 128 + w] = f2bf(tile[r][w] * inv[r]);
  }
  for (int e = tid; e < 8192; e += 256) {
    int w = e >> 6, r = e & 63;
    mem_t[(size_t)w * 16384 + n0 + r] = f2bf(tile[r][w]);
  }
}

__global__ __launch_bounds__(256) void rv_reduce(
    const float* __restrict__ part, unsigned short* __restrict__ ci_h)
{
  int e = blockIdx.x * 256 + threadIdx.x;   // 16384
  float s = 0.0f;
  for (int z = 0; z < 64; ++z) s += part[(size_t)z * 16384 + e];
  int b = e >> 7, w = e & 127;
  ci_h[b * 1664 + 512 + w] = f2bf(sat(s));
}

__global__ void init_weights(
    const void* __restrict__ rkW, const void* __restrict__ wkW,
    const void* __restrict__ erW, const void* __restrict__ adW,
    const void* __restrict__ rbW, const void* __restrict__ rgW,
    const void* __restrict__ wbW, const void* __restrict__ wgW,
    unsigned short* __restrict__ Whead, unsigned short* __restrict__ Wsc,
    const int* __restrict__ flags)
{
  const int F = flags[1];
  const long T2 = 512L * 960, T3 = 4L * 960;
  for (long e = (long)blockIdx.x * 256 + threadIdx.x; e < T2 + T3;
       e += (long)gridDim.x * 256) {
    if (e < T2) {
      int r = (int)(e / 960), k = (int)(e % 960);
      unsigned short v = 0;
      if (k < 899) {
        if (r < 128) v = f2bf(ldx(rkW, F, (long)r * 899 + k));
        else if (r < 256) v = f2bf(ldx(wkW, F, (long)(r - 128) * 899 + k));
        else if (r < 384) v = f2bf(ldx(erW, F, (long)(r - 256) * 899 + k));
        else v = f2bf(ldx(adW, F, (long)(r - 384) * 899 + k));
      }
      Whead[e] = v;
    } else {
      long e3 = e - T2; int r = (int)(e3 / 960), k = (int)(e3 % 960);
      const void* src = (r == 0) ? rbW : (r == 1) ? rgW : (r == 2) ? wbW : wgW;
      Wsc[e3] = (k < 899) ? f2bf(ldx(src, F, k)) : (unsigned short)0;
    }
  }
}

__global__ void init_state(
    const void* __restrict__ x, unsigned short* __restrict__ ci_h,
    float* __restrict__ c, float* __restrict__ rw,
    unsigned short* __restrict__ co_bf, const int* __restrict__ flags)
{
  const int F = flags[1];
  const long T1 = 128L * 1664, T2 = 128L * 1024, T3 = 128L * 16384, T5 = 128L * 960;
  const long total = T1 + T2 + T3 + T5;
  for (long e = (long)blockIdx.x * 256 + threadIdx.x; e < total;
       e += (long)gridDim.x * 256) {
    if (e < T1) {
      int b = (int)(e / 1664), k = (int)(e % 1664);
      ci_h[e] = (k < 512) ? f2bf(ldx(x, F, (long)b * 16384 + k)) : (unsigned short)0;
    } else if (e < T1 + T2) {
      c[e - T1] = 0.0f;
    } else if (e < T1 + T2 + T3) {
      rw[e - T1 - T2] = 1.0f / 16384.0f;
    } else {
      co_bf[e - T1 - T2 - T3] = 0;
    }
  }
}

extern "C" void kernel_launch(void* const* d_in, const int* in_sizes, int n_in,
                              void* d_out, int out_size, void* d_ws, size_t ws_size,
                              hipStream_t stream) {
  const void* x      = d_in[0];
  const void* memory = d_in[1];
  const void* Wih    = d_in[2];
  const void* Whh    = d_in[3];
  const void* bih    = d_in[4];
  const void* bhh    = d_in[5];
  const void* Wout   = d_in[6];
  const void* bout   = d_in[7];
  const void* rkW    = d_in[8];
  const void* rkb    = d_in[9];
  const void* rbW    = d_in[10];
  const void* rbb    = d_in[11];
  const void* rgW    = d_in[12];
  const void* rgb    = d_in[13];
  const void* wkW    = d_in[14];
  const void* wkb    = d_in[15];
  const void* wbW    = d_in[16];
  const void* wbb    = d_in[17];
  const void* wgW    = d_in[18];
  const void* wgb    = d_in[19];
  const void* erW    = d_in[20];
  const void* erb    = d_in[21];
  const void* adW    = d_in[22];
  const void* adb    = d_in[23];
  const void* pW     = d_in[24];
  const void* pb     = d_in[25];

  char* p = (char*)d_ws;
  auto alloc = [&](size_t bytes) -> char* {
    char* r = p; p += (bytes + 255) & ~(size_t)255; return r;
  };
  // big: Csim [256,16384] bf16 -> Cea [16384,256] bf16 -> part [64,16384] f32
  char*           big    = alloc(256L * 16384 * 4);
  unsigned short* Whead  = (unsigned short*)alloc(512L * 960 * 2);
  unsigned short* Wsc    = (unsigned short*)alloc(4L * 960 * 2);
  unsigned short* ci_h   = (unsigned short*)alloc(128L * 1664 * 2);
  float*          Cg     = (float*)alloc(128L * 4096 * 4);
  float*          c      = (float*)alloc(128L * 1024 * 4);
  unsigned short* co_bf  = (unsigned short*)alloc(128L * 960 * 2);
  float*          Hout   = (float*)alloc(512L * 128 * 4);
  unsigned short* keys_n = (unsigned short*)alloc(256L * 128 * 2);
  unsigned short* EA     = (unsigned short*)alloc(256L * 128 * 2);
  float*          sc     = (float*)alloc(4L * 128 * 4);
  float*          rw     = (float*)alloc(128L * 16384 * 4);
  unsigned short* ww_nat = (unsigned short*)alloc(128L * 16384 * 2);
  unsigned short* ww_t   = (unsigned short*)alloc(16384L * 128 * 2);
  float*          mem    = (float*)alloc(16384L * 128 * 4);
  unsigned short* memn   = (unsigned short*)alloc(16384L * 128 * 2);
  unsigned short* mem_t  = (unsigned short*)alloc(128L * 16384 * 2);
  int*            flags  = (int*)alloc(256);

  probe_dtype<<<1, 64, 0, stream>>>((const unsigned int*)Whh, flags);
  probe_layout<<<1, 64, 0, stream>>>(flags);
  init_weights<<<2048, 256, 0, stream>>>(rkW, wkW, erW, adW, rbW, rgW, wbW, wgW,
                                         Whead, Wsc, flags);
  init_state<<<8192, 256, 0, stream>>>(x, ci_h, c, rw, co_bf, flags);
  init_mem<<<256, 256, 0, stream>>>(memory, mem, memn, mem_t, flags);

  for (int t = 0; t < 32; ++t) {
    // LSTM gates: Cg = [xt|rv] @ Wih^T  +  h @ Whh^T
    gemm_bt<128, 64, 0, 0><<<dim3(1, 64, 1), 256, 0, stream>>>(
        ci_h, 1664, Wih, 640, 128, 4096, 640, 640, Cg, 4096,
        nullptr, nullptr, 0, flags, 0, 1, 0, 0);
    gemm_bt<128, 64, 0, 1><<<dim3(1, 64, 1), 256, 0, stream>>>(
        ci_h + 640, 1664, Whh, 1024, 128, 4096, 1024, 1024, Cg, 4096,
        nullptr, nullptr, 0, flags, 0, 1, 0, 0);
    lstm_ew<<<768, 256, 0, stream>>>(Cg, bih, bhh, c, ci_h, x, t, flags);
    // co = h @ Wout^T + bout -> bf16 co_bf [128][960]
    gemm_bt<128, 64, 1, 0><<<dim3(1, 15, 1), 256, 0, stream>>>(
        ci_h + 640, 1664, Wout, 1024, 128, 899, 1024, 1024, nullptr, 960,
        bout, co_bf, 0, flags, 0, 1, 1, 0);
    // Hout[512][128] = Whead @ co_bf^T
    gemm_bt<128, 128, 0, 0><<<dim3(4, 1, 1), 256, 0, stream>>>(
        Whead, 960, co_bf, 960, 512, 128, 960, 960, Hout, 128,
        nullptr, nullptr, 0, flags, 0, 0, 0, 0);
    heads_post_keys<<<256, 128, 0, stream>>>(Hout, rkb, wkb, keys_n, flags);
    heads_post_ea<<<128, 256, 0, stream>>>(Hout, erb, adb, EA, flags);
    scalar_heads<<<2, 256, 0, stream>>>(Wsc, co_bf, rbb, rgb, wbb, wgb, sc, flags);
    // out = co[:, :512] @ pW^T + pb -> d_out at element offset t*512
    gemm_bt<128, 64, 1, 0><<<dim3(1, 8, 1), 256, 0, stream>>>(
        co_bf, 960, pW, 512, 128, 512, 512, 512, nullptr, 16384,
        pb, d_out, (long long)t * 512, flags, 0, 1, 1, 1);
    // sim -> big (bf16 Csim)
    gemm_bt<128, 128, 1, 0><<<dim3(2, 128, 1), 256, 0, stream>>>(
        keys_n, 128, memn, 128, 256, 16384, 128, 128, nullptr, 16384,
        nullptr, big, 0, flags, 0, 0, 0, 0);
    softmax_interp<<<256, 256, 0, stream>>>((const unsigned short*)big, sc, rw, ww_nat);
    transpose_ww<<<dim3(256, 2, 1), 256, 0, stream>>>(ww_nat, ww_t);
    // [erase|add][16384,256] -> big (bf16 Cea)
    gemm_bt<128, 128, 1, 0><<<dim3(128, 2, 1), 256, 0, stream>>>(
        ww_t, 128, EA, 128, 16384, 256, 128, 128, nullptr, 256,
        nullptr, big, 0, flags, 0, 0, 0, 0);
    mem_update<<<256, 256, 0, stream>>>((const unsigned short*)big, mem, memn, mem_t);
    // rv = rw(fp32) @ mem_t^T, split-K 64 -> big (f32 part)
    gemm_bt<128, 128, 2, 0><<<dim3(1, 1, 64), 256, 0, stream>>>(
        rw, 16384, mem_t, 16384, 128, 128, 16384, 256, (float*)big, 128,
        nullptr, nullptr, 0, flags, 2, 0, 0, 0);
    rv_reduce<<<64, 256, 0, stream>>>((const float*)big, ci_h);
  }
}

// Round 4
// 4127.930 us; speedup vs baseline: 2.9562x; 2.9562x over previous
//
#include <hip/hip_runtime.h>

typedef __attribute__((ext_vector_type(8))) short bf16x8;
typedef __attribute__((ext_vector_type(4))) float f32x4;

__device__ __forceinline__ float bf2f(unsigned short u) {
  union { float f; unsigned int i; } v; v.i = ((unsigned int)u) << 16; return v.f;
}
__device__ __forceinline__ unsigned short f2bf(float f) {
  union { float f; unsigned int i; } v; v.f = f;
  unsigned int r = v.i + 0x7fffu + ((v.i >> 16) & 1u);
  return (unsigned short)(r >> 16);
}
__device__ __forceinline__ float sigf(float x) { return 1.0f / (1.0f + expf(-x)); }
__device__ __forceinline__ float softplusf(float x) {
  return (x > 20.0f) ? x : log1pf(expf(x));
}
// NaN firewall: fmaxf(NaN,-1e6) = -1e6 => outputs provably finite
__device__ __forceinline__ float sat(float v) {
  return fminf(fmaxf(v, -1.0e6f), 1.0e6f);
}
__device__ __forceinline__ float ldx(const void* p, int is32, long i) {
  return is32 ? ((const float*)p)[i] : bf2f(((const unsigned short*)p)[i]);
}
template<int A32>
__device__ __forceinline__ bf16x8 load8(const void* base, long off) {
  if (A32) {
    const float* p = (const float*)base + off;
    f32x4 a = *(const f32x4*)p;
    f32x4 b = *(const f32x4*)(p + 4);
    bf16x8 r;
    r[0] = (short)f2bf(a[0]); r[1] = (short)f2bf(a[1]);
    r[2] = (short)f2bf(a[2]); r[3] = (short)f2bf(a[3]);
    r[4] = (short)f2bf(b[0]); r[5] = (short)f2bf(b[1]);
    r[6] = (short)f2bf(b[2]); r[7] = (short)f2bf(b[3]);
    return r;
  }
  return *(const bf16x8*)((const unsigned short*)base + off);
}

// flags[0] = C/D layout swap, flags[1] = input dtype (0=bf16, 1=fp32)

__global__ __launch_bounds__(64) void probe_dtype(
    const unsigned int* __restrict__ w, int* __restrict__ flags)
{
  const int lane = threadIdx.x;
  int cnt = 0;
  for (int i = 0; i < 16; ++i) {
    unsigned int word = w[lane * 16 + i];
    float av = fabsf(bf2f((unsigned short)(word & 0xFFFFu)));
    if (av > 1.0e-4f && av < 1.0f) cnt++;
  }
  #pragma unroll
  for (int off = 32; off > 0; off >>= 1) cnt += __shfl_xor(cnt, off);
  if (lane == 0) flags[1] = (cnt > 512) ? 0 : 1;
}

__global__ __launch_bounds__(64) void probe_layout(int* __restrict__ flags) {
  const int lane = threadIdx.x;
  const int qr = lane & 15, quad = lane >> 4;
  bf16x8 a, b;
  #pragma unroll
  for (int j = 0; j < 8; ++j) {
    int k = quad * 8 + j;
    a[j] = (short)f2bf((k == qr) ? 1.0f : 0.0f);
    b[j] = (short)f2bf((float)(k + 1));
  }
  f32x4 acc = {0.0f, 0.0f, 0.0f, 0.0f};
  acc = __builtin_amdgcn_mfma_f32_16x16x32_bf16(a, b, acc, 0, 0, 0);
  bool ok0 = true, ok1 = true;
  #pragma unroll
  for (int rg = 0; rg < 4; ++rg) {
    ok0 = ok0 && (acc[rg] == (float)(quad * 4 + rg + 1));
    ok1 = ok1 && (acc[rg] == (float)(qr + 1));
  }
  int a0 = __all(ok0 ? 1 : 0);
  int a1 = __all(ok1 ? 1 : 0);
  if (lane == 0) flags[0] = a0 ? 0 : (a1 ? 1 : 0);
}

// ---------------------------------------------------------------------------
// Double-buffered MFMA GEMM: C[M,N] = A[M,K] * B[N,K]^T. All dims are exact
// tile multiples (no bounds checks). One __syncthreads per K-iter; global
// loads for tile i+1 issue before tile i's MFMA (latency overlap).
// EPI 0: fp32 store. EPI 2: bf16 store. EPI 3: split-K fp32 partial.
// A32: 1 = A is fp32 (converted in loader). B is always bf16.
// ---------------------------------------------------------------------------
template<int BM, int BN, int EPI, int A32>
__global__ __launch_bounds__(256) void gemm_pipe(
    const void* __restrict__ A, int lda,
    const unsigned short* __restrict__ B, int ldb,
    int kChunk, int Mtot, int Ntot,
    float* __restrict__ C, long long ldc, unsigned short* __restrict__ Cb,
    const int* __restrict__ flags)
{
  constexpr int LDT = 72;
  constexpr int AI = BM / 32;
  constexpr int BI = BN / 32;
  __shared__ unsigned short smem[2][(BM + BN) * LDT];
  const int tid = threadIdx.x;
  const int lane = tid & 63, wid = tid >> 6;
  const int wm = wid & 1, wn = wid >> 1;
  constexpr int WM = BM / 2, WN = BN / 2;
  constexpr int TM = WM / 16, TN = WN / 16;
  const int m0 = blockIdx.x * BM, n0 = blockIdx.y * BN;
  const int kBeg = blockIdx.z * kChunk;
  const int qr = lane & 15, quad = lane >> 4;
  const int NIT = kChunk >> 6;

  f32x4 acc[TM][TN] = {};
  bf16x8 ar[AI], br[BI];

  auto loadAB = [&](int k0) {
    #pragma unroll
    for (int i = 0; i < AI; ++i) {
      int lin = i * 256 + tid; int row = lin >> 3, q = (lin & 7) << 3;
      ar[i] = load8<A32>(A, (long)(m0 + row) * lda + k0 + q);
    }
    #pragma unroll
    for (int i = 0; i < BI; ++i) {
      int lin = i * 256 + tid; int row = lin >> 3, q = (lin & 7) << 3;
      br[i] = *(const bf16x8*)(B + (long)(n0 + row) * ldb + k0 + q);
    }
  };
  auto stage = [&](int buf) {
    #pragma unroll
    for (int i = 0; i < AI; ++i) {
      int lin = i * 256 + tid; int row = lin >> 3, q = (lin & 7) << 3;
      *(bf16x8*)&smem[buf][row * LDT + q] = ar[i];
    }
    #pragma unroll
    for (int i = 0; i < BI; ++i) {
      int lin = i * 256 + tid; int row = lin >> 3, q = (lin & 7) << 3;
      *(bf16x8*)&smem[buf][(BM + row) * LDT + q] = br[i];
    }
  };

  loadAB(kBeg);
  stage(0);
  __syncthreads();
  for (int it = 0; it < NIT; ++it) {
    if (it + 1 < NIT) loadAB(kBeg + (it + 1) * 64);
    const unsigned short* As = &smem[it & 1][0];
    const unsigned short* Bs = &smem[it & 1][BM * LDT];
    #pragma unroll
    for (int ks = 0; ks < 64; ks += 32) {
      bf16x8 af[TM], bfv[TN];
      #pragma unroll
      for (int mt = 0; mt < TM; ++mt)
        af[mt] = *(const bf16x8*)&As[(wm * WM + mt * 16 + qr) * LDT + ks + quad * 8];
      #pragma unroll
      for (int nt = 0; nt < TN; ++nt)
        bfv[nt] = *(const bf16x8*)&Bs[(wn * WN + nt * 16 + qr) * LDT + ks + quad * 8];
      #pragma unroll
      for (int mt = 0; mt < TM; ++mt)
        #pragma unroll
        for (int nt = 0; nt < TN; ++nt)
          acc[mt][nt] = __builtin_amdgcn_mfma_f32_16x16x32_bf16(af[mt], bfv[nt], acc[mt][nt], 0, 0, 0);
    }
    if (it + 1 < NIT) { stage((it + 1) & 1); __syncthreads(); }
  }

  const int swap = flags[0];
  #pragma unroll
  for (int mt = 0; mt < TM; ++mt)
    #pragma unroll
    for (int nt = 0; nt < TN; ++nt)
      #pragma unroll
      for (int rg = 0; rg < 4; ++rg) {
        int ri = swap ? qr : (quad * 4 + rg);
        int ci = swap ? (quad * 4 + rg) : qr;
        int gm = m0 + wm * WM + mt * 16 + ri;
        int gn = n0 + wn * WN + nt * 16 + ci;
        float v = sat(acc[mt][nt][rg]);
        if (EPI == 0) C[(size_t)gm * ldc + gn] = v;
        else if (EPI == 2) Cb[(size_t)gm * ldc + gn] = f2bf(v);
        else C[(size_t)blockIdx.z * Mtot * Ntot + (size_t)gm * Ntot + gn] = v;
      }
}

// ---------------------------------------------------------------------------
// Heads mega-GEMM: H[1152,128] = Wcomb[1152,1024] @ h[128,1024]^T (+vcat).
// grid (9, 2), BM=128, BN=64. Per-m0 epilogue:
//   m0 0/128: rkey/wkey -> column L2-norm -> keys_n[head*128+b][w]
//   m0 256:   sigmoid -> EA[w][b];  m0 384: tanh -> EA[128+w][b]
//   m0 512..896: out -> d_out[b][t][o]  (dtype-dispatched)
//   m0 1024:  softplus -> sc (rows 1024..1027)
// ---------------------------------------------------------------------------
__global__ __launch_bounds__(256) void gemm_heads(
    const unsigned short* __restrict__ Wcomb,
    const unsigned short* __restrict__ h, int ldb,
    const float* __restrict__ vcat,
    unsigned short* __restrict__ keys_n, unsigned short* __restrict__ EA,
    float* __restrict__ sc, void* __restrict__ outp, int t,
    const int* __restrict__ flags)
{
  constexpr int BM = 128, BN = 64, LDT = 72;
  __shared__ unsigned short smem[2][(BM + BN) * LDT];
  __shared__ float colss[64];
  __shared__ float cinv[64];
  const int tid = threadIdx.x;
  const int lane = tid & 63, wid = tid >> 6;
  const int wm = wid & 1, wn = wid >> 1;
  constexpr int TM = 4, TN = 2;
  const int m0 = blockIdx.x * BM, n0 = blockIdx.y * BN;
  const int qr = lane & 15, quad = lane >> 4;
  const int NIT = 16;  // K = 1024

  f32x4 acc[TM][TN] = {};
  bf16x8 ar[4], br[2];
  auto loadAB = [&](int k0) {
    #pragma unroll
    for (int i = 0; i < 4; ++i) {
      int lin = i * 256 + tid; int row = lin >> 3, q = (lin & 7) << 3;
      ar[i] = *(const bf16x8*)(Wcomb + (long)(m0 + row) * 1024 + k0 + q);
    }
    #pragma unroll
    for (int i = 0; i < 2; ++i) {
      int lin = i * 256 + tid; int row = lin >> 3, q = (lin & 7) << 3;
      br[i] = *(const bf16x8*)(h + (long)(n0 + row) * ldb + k0 + q);
    }
  };
  auto stage = [&](int buf) {
    #pragma unroll
    for (int i = 0; i < 4; ++i) {
      int lin = i * 256 + tid; int row = lin >> 3, q = (lin & 7) << 3;
      *(bf16x8*)&smem[buf][row * LDT + q] = ar[i];
    }
    #pragma unroll
    for (int i = 0; i < 2; ++i) {
      int lin = i * 256 + tid; int row = lin >> 3, q = (lin & 7) << 3;
      *(bf16x8*)&smem[buf][(BM + row) * LDT + q] = br[i];
    }
  };

  loadAB(0);
  stage(0);
  __syncthreads();
  for (int it = 0; it < NIT; ++it) {
    if (it + 1 < NIT) loadAB((it + 1) * 64);
    const unsigned short* As = &smem[it & 1][0];
    const unsigned short* Bs = &smem[it & 1][BM * LDT];
    #pragma unroll
    for (int ks = 0; ks < 64; ks += 32) {
      bf16x8 af[TM], bfv[TN];
      #pragma unroll
      for (int mt = 0; mt < TM; ++mt)
        af[mt] = *(const bf16x8*)&As[(wm * 64 + mt * 16 + qr) * LDT + ks + quad * 8];
      #pragma unroll
      for (int nt = 0; nt < TN; ++nt)
        bfv[nt] = *(const bf16x8*)&Bs[(wn * 32 + nt * 16 + qr) * LDT + ks + quad * 8];
      #pragma unroll
      for (int mt = 0; mt < TM; ++mt)
        #pragma unroll
        for (int nt = 0; nt < TN; ++nt)
          acc[mt][nt] = __builtin_amdgcn_mfma_f32_16x16x32_bf16(af[mt], bfv[nt], acc[mt][nt], 0, 0, 0);
    }
    if (it + 1 < NIT) { stage((it + 1) & 1); __syncthreads(); }
  }

  const int swap = flags[0];
  const int F = flags[1];
  // add vcat (bias) in-place
  #pragma unroll
  for (int mt = 0; mt < TM; ++mt)
    #pragma unroll
    for (int nt = 0; nt < TN; ++nt)
      #pragma unroll
      for (int rg = 0; rg < 4; ++rg) {
        int ri = swap ? qr : (quad * 4 + rg);
        int gm = m0 + wm * 64 + mt * 16 + ri;
        acc[mt][nt][rg] = sat(acc[mt][nt][rg] + vcat[gm]);
      }

  if (m0 < 256) {
    if (tid < 64) colss[tid] = 0.0f;
    __syncthreads();
    #pragma unroll
    for (int nt = 0; nt < TN; ++nt)
      #pragma unroll
      for (int rg = 0; rg < 4; ++rg) {
        float part = 0.0f;
        #pragma unroll
        for (int mt = 0; mt < TM; ++mt) {
          float v = acc[mt][nt][rg]; part += v * v;
        }
        int ci = swap ? (quad * 4 + rg) : qr;
        atomicAdd(&colss[wn * 32 + nt * 16 + ci], part);
      }
    __syncthreads();
    if (tid < 64) cinv[tid] = 1.0f / fmaxf(sqrtf(colss[tid]), 1e-12f);
    __syncthreads();
    const int head = m0 >> 7;
    #pragma unroll
    for (int mt = 0; mt < TM; ++mt)
      #pragma unroll
      for (int nt = 0; nt < TN; ++nt)
        #pragma unroll
        for (int rg = 0; rg < 4; ++rg) {
          int ri = swap ? qr : (quad * 4 + rg);
          int ci = swap ? (quad * 4 + rg) : qr;
          int w = wm * 64 + mt * 16 + ri;
          int cl = wn * 32 + nt * 16 + ci;
          keys_n[(size_t)(head * 128 + n0 + cl) * 128 + w] =
              f2bf(acc[mt][nt][rg] * cinv[cl]);
        }
  } else {
    #pragma unroll
    for (int mt = 0; mt < TM; ++mt)
      #pragma unroll
      for (int nt = 0; nt < TN; ++nt)
        #pragma unroll
        for (int rg = 0; rg < 4; ++rg) {
          int ri = swap ? qr : (quad * 4 + rg);
          int ci = swap ? (quad * 4 + rg) : qr;
          int gm = m0 + wm * 64 + mt * 16 + ri;
          int gn = n0 + wn * 32 + nt * 16 + ci;
          float v = acc[mt][nt][rg];
          if (m0 == 256) {
            EA[(size_t)(gm - 256) * 128 + gn] = f2bf(sigf(v));
          } else if (m0 == 384) {
            EA[(size_t)(gm - 256) * 128 + gn] = f2bf(tanhf(v));
          } else if (m0 < 1024) {
            int o = gm - 512;
            size_t idx = (size_t)gn * 16384 + (size_t)t * 512 + o;
            if (F) ((float*)outp)[idx] = v;
            else ((unsigned short*)outp)[idx] = f2bf(v);
          } else if (gm < 1028) {
            float sp = fminf(softplusf(v), 1.0e4f);
            int j = gm - 1024;
            sc[j * 128 + gn] = (j & 1) ? (1.0f + sp) : sp;
          }
        }
  }
}

// ---------------------------------------------------------------------------
// LSTM elementwise + stage next xt. ci_h row: [xt 512 | rv 128 | h 1024]
// ---------------------------------------------------------------------------
__global__ __launch_bounds__(256) void lstm_ew(
    const float* __restrict__ Cg, const float* __restrict__ bsum,
    float* __restrict__ c, unsigned short* __restrict__ ci_h,
    const unsigned short* __restrict__ x_bf, int t)
{
  const int bx = blockIdx.x;
  if (bx < 512) {
    int idx = bx * 256 + threadIdx.x;          // 128*1024
    int b = idx >> 10, j = idx & 1023;
    const float* g = Cg + (size_t)b * 4096;
    float iv = g[j]        + bsum[j];
    float fv = g[1024 + j] + bsum[1024 + j];
    float gv = g[2048 + j] + bsum[2048 + j];
    float ov = g[3072 + j] + bsum[3072 + j];
    float cn = sat(sigf(fv) * c[idx] + sigf(iv) * tanhf(gv));
    c[idx] = cn;
    ci_h[b * 1664 + 640 + j] = f2bf(sigf(ov) * tanhf(cn));
  } else if (t + 1 < 32) {
    int e = (bx - 512) * 256 + threadIdx.x;    // 128*512
    int b = e >> 9, k = e & 511;
    ci_h[b * 1664 + k] = x_bf[(size_t)(t + 1) * 65536 + e];
  }
}

__global__ __launch_bounds__(256) void softmax_interp(
    const unsigned short* __restrict__ Csim, const float* __restrict__ sc,
    float* __restrict__ rw, unsigned short* __restrict__ ww_nat)
{
  const int r = blockIdx.x, tid = threadIdx.x;
  const int b = r & 127;
  const bool isRead = r < 128;
  const float beta  = isRead ? sc[b]       : sc[256 + b];
  const float gamma = isRead ? sc[128 + b] : sc[384 + b];
  const unsigned short* row = Csim + (size_t)r * 16384;
  __shared__ float red[4];
  float mx = -3.0e38f;
  for (int i = tid; i < 16384; i += 256) mx = fmaxf(mx, bf2f(row[i]));
  #pragma unroll
  for (int off = 32; off > 0; off >>= 1) mx = fmaxf(mx, __shfl_xor(mx, off));
  if ((tid & 63) == 0) red[tid >> 6] = mx;
  __syncthreads();
  mx = fmaxf(fmaxf(red[0], red[1]), fmaxf(red[2], red[3]));
  const float m = beta * mx;
  __syncthreads();
  float s = 0.0f;
  for (int i = tid; i < 16384; i += 256) s += expf(beta * bf2f(row[i]) - m);
  #pragma unroll
  for (int off = 32; off > 0; off >>= 1) s += __shfl_xor(s, off);
  if ((tid & 63) == 0) red[tid >> 6] = s;
  __syncthreads();
  s = red[0] + red[1] + red[2] + red[3];
  const float inv = 1.0f / fmaxf(s, 1e-30f);
  if (isRead) {
    float* prow = rw + (size_t)b * 16384;
    for (int i = tid; i < 16384; i += 256) {
      float p = expf(beta * bf2f(row[i]) - m) * inv;
      prow[i] = sat(gamma * p + (1.0f - gamma) * prow[i]);
    }
  } else {
    unsigned short* wrow = ww_nat + (size_t)b * 16384;
    const float u = 1.0f / 16384.0f;
    for (int i = tid; i < 16384; i += 256) {
      float p = expf(beta * bf2f(row[i]) - m) * inv;
      wrow[i] = f2bf(sat(gamma * p + (1.0f - gamma) * u));
    }
  }
}

// [128][16384] bf16 -> [16384][128] bf16
__global__ __launch_bounds__(256) void transpose_ww(
    const unsigned short* __restrict__ src, unsigned short* __restrict__ dst)
{
  __shared__ unsigned short tile[64][65];
  const int n0 = blockIdx.x * 64, b0 = blockIdx.y * 64;
  for (int e = threadIdx.x; e < 4096; e += 256) {
    int rb = e >> 6, cn = e & 63;
    tile[rb][cn] = src[(size_t)(b0 + rb) * 16384 + n0 + cn];
  }
  __syncthreads();
  for (int e = threadIdx.x; e < 4096; e += 256) {
    int rn = e >> 6, cb = e & 63;
    dst[(size_t)(n0 + rn) * 128 + b0 + cb] = tile[cb][rn];
  }
}

__global__ __launch_bounds__(256) void mem_update(
    const unsigned short* __restrict__ Cea, float* __restrict__ mem,
    unsigned short* __restrict__ memn, unsigned short* __restrict__ mem_t)
{
  __shared__ float tile[64][129];
  __shared__ float inv[64];
  const int n0 = blockIdx.x * 64, tid = threadIdx.x;
  for (int e = tid; e < 8192; e += 256) {
    int r = e >> 7, w = e & 127;
    size_t gi = (size_t)(n0 + r) * 128 + w;
    float er = bf2f(Cea[(size_t)(n0 + r) * 256 + w]);
    float ad = bf2f(Cea[(size_t)(n0 + r) * 256 + 128 + w]);
    float nv = sat(mem[gi] * (1.0f - er) + ad);
    mem[gi] = nv;
    tile[r][w] = nv;
  }
  __syncthreads();
  if (tid < 64) {
    float ss = 0.0f;
    for (int w = 0; w < 128; ++w) { float v = tile[tid][w]; ss += v * v; }
    inv[tid] = 1.0f / fmaxf(sqrtf(ss), 1e-12f);
  }
  __syncthreads();
  for (int e = tid; e < 8192; e += 256) {
    int r = e >> 7, w = e & 127;
    memn[(size_t)(n0 + r) * 128 + w] = f2bf(tile[r][w] * inv[r]);
  }
  for (int e = tid; e < 8192; e += 256) {
    int w = e >> 6, r = e & 63;
    mem_t[(size_t)w * 16384 + n0 + r] = f2bf(tile[r][w]);
  }
}

__global__ __launch_bounds__(256) void init_mem(
    const void* __restrict__ memory, float* __restrict__ mem,
    unsigned short* __restrict__ memn, unsigned short* __restrict__ mem_t,
    const int* __restrict__ flags)
{
  const int F = flags[1];
  __shared__ float tile[64][129];
  __shared__ float inv[64];
  const int n0 = blockIdx.x * 64, tid = threadIdx.x;
  for (int e = tid; e < 8192; e += 256) {
    int r = e >> 7, w = e & 127;
    size_t gi = (size_t)(n0 + r) * 128 + w;
    float nv = ldx(memory, F, (long)gi);
    mem[gi] = nv;
    tile[r][w] = nv;
  }
  __syncthreads();
  if (tid < 64) {
    float ss = 0.0f;
    for (int w = 0; w < 128; ++w) { float v = tile[tid][w]; ss += v * v; }
    inv[tid] = 1.0f / fmaxf(sqrtf(ss), 1e-12f);
  }
  __syncthreads();
  for (int e = tid; e < 8192; e += 256) {
    int r = e >> 7, w = e & 127;
    memn[(size_t)(n0 + r) * 128 + w] = f2bf(tile[r][w] * inv[r]);
  }
  for (int e = tid; e < 8192; e += 256) {
    int w = e >> 6, r = e & 63;
    mem_t[(size_t)w * 16384 + n0 + r] = f2bf(tile[r][w]);
  }
}

__global__ __launch_bounds__(256) void rv_reduce(
    const float* __restrict__ part, unsigned short* __restrict__ ci_h)
{
  int e = blockIdx.x * 256 + threadIdx.x;   // 16384
  float s = 0.0f;
  for (int z = 0; z < 64; ++z) s += part[(size_t)z * 16384 + e];
  int b = e >> 7, w = e & 127;
  ci_h[b * 1664 + 512 + w] = f2bf(sat(s));
}

// ---------------------------------------------------------------------------
// Big init: W_lstm, bsum, x_bf, Wcat, ci_h, c, rw — one grid-stride kernel.
// ---------------------------------------------------------------------------
__global__ void init_pack(
    const void* __restrict__ x, const void* __restrict__ Wih,
    const void* __restrict__ Whh, const void* __restrict__ bih,
    const void* __restrict__ bhh,
    const void* __restrict__ rkW, const void* __restrict__ wkW,
    const void* __restrict__ erW, const void* __restrict__ adW,
    const void* __restrict__ pW,
    const void* __restrict__ rbW, const void* __restrict__ rgW,
    const void* __restrict__ wbW, const void* __restrict__ wgW,
    unsigned short* __restrict__ W_lstm, float* __restrict__ bsum,
    unsigned short* __restrict__ x_bf, unsigned short* __restrict__ Wcat,
    unsigned short* __restrict__ ci_h, float* __restrict__ c,
    float* __restrict__ rw, const int* __restrict__ flags)
{
  const int F = flags[1];
  const long T0 = 4096L * 1664;            // W_lstm
  const long T1 = 4096;                    // bsum
  const long T2 = 32L * 128 * 512;         // x_bf [t][b][k]
  const long T3 = 1152L * 960;             // Wcat
  const long T4 = 128L * 1664;             // ci_h
  const long T5 = 128L * 1024;             // c
  const long T6 = 128L * 16384;            // rw
  const long total = T0 + T1 + T2 + T3 + T4 + T5 + T6;
  for (long e = (long)blockIdx.x * 256 + threadIdx.x; e < total;
       e += (long)gridDim.x * 256) {
    long r = e;
    if (r < T0) {
      int j = (int)(r / 1664), k = (int)(r % 1664);
      float v = (k < 640) ? ldx(Wih, F, (long)j * 640 + k)
                          : ldx(Whh, F, (long)j * 1024 + (k - 640));
      W_lstm[r] = f2bf(v);
      continue;
    }
    r -= T0;
    if (r < T1) { bsum[r] = ldx(bih, F, r) + ldx(bhh, F, r); continue; }
    r -= T1;
    if (r < T2) {
      int t = (int)(r >> 16); long rr = r & 65535;
      int b = (int)(rr >> 9), k = (int)(rr & 511);
      x_bf[r] = f2bf(ldx(x, F, (long)b * 16384 + (long)t * 512 + k));
      continue;
    }
    r -= T2;
    if (r < T3) {
      int j = (int)(r / 960), o = (int)(r % 960);
      float v = 0.0f;
      if (j < 512) {
        if (o < 899) {
          if (j < 128) v = ldx(rkW, F, (long)j * 899 + o);
          else if (j < 256) v = ldx(wkW, F, (long)(j - 128) * 899 + o);
          else if (j < 384) v = ldx(erW, F, (long)(j - 256) * 899 + o);
          else v = ldx(adW, F, (long)(j - 384) * 899 + o);
        }
      } else if (j < 1024) {
        if (o < 512) v = ldx(pW, F, (long)(j - 512) * 512 + o);
      } else if (j < 1028) {
        if (o < 899) {
          const void* s = (j == 1024) ? rbW : (j == 1025) ? rgW
                        : (j == 1026) ? wbW : wgW;
          v = ldx(s, F, o);
        }
      }
      Wcat[r] = f2bf(v);
      continue;
    }
    r -= T3;
    if (r < T4) {
      int b = (int)(r / 1664), k = (int)(r % 1664);
      ci_h[r] = (k < 512) ? f2bf(ldx(x, F, (long)b * 16384 + k)) : (unsigned short)0;
      continue;
    }
    r -= T4;
    if (r < T5) { c[r] = 0.0f; continue; }
    r -= T5;
    rw[r] = 1.0f / 16384.0f;
  }
}

// WoutT[n][o] = Wout[o][n] (o<899, else 0), n<1024, o<960. bf16 out.
__global__ __launch_bounds__(256) void transpose_wout(
    const void* __restrict__ Wout, unsigned short* __restrict__ WoutT,
    const int* __restrict__ flags)
{
  const int F = flags[1];
  __shared__ float tile[64][65];
  const int n0 = blockIdx.x * 64, o0 = blockIdx.y * 64;
  for (int e = threadIdx.x; e < 4096; e += 256) {
    int ro = e >> 6, cn = e & 63;
    int o = o0 + ro;
    tile[ro][cn] = (o < 899) ? ldx(Wout, F, (long)o * 1024 + n0 + cn) : 0.0f;
  }
  __syncthreads();
  for (int e = threadIdx.x; e < 4096; e += 256) {
    int rn = e >> 6, co = e & 63;
    WoutT[(size_t)(n0 + rn) * 960 + o0 + co] = f2bf(tile[co][rn]);
  }
}

// vcat[j] = sum_o srcW(j,o)*bout[o] + bias_j   (fp32)
__global__ __launch_bounds__(64) void init_vcat(
    const void* __restrict__ rkW, const void* __restrict__ wkW,
    const void* __restrict__ erW, const void* __restrict__ adW,
    const void* __restrict__ pW,
    const void* __restrict__ rbW, const void* __restrict__ rgW,
    const void* __restrict__ wbW, const void* __restrict__ wgW,
    const void* __restrict__ bout,
    const void* __restrict__ rkb, const void* __restrict__ wkb,
    const void* __restrict__ erb, const void* __restrict__ adb,
    const void* __restrict__ pb,
    const void* __restrict__ rbb, const void* __restrict__ rgb,
    const void* __restrict__ wbb, const void* __restrict__ wgb,
    float* __restrict__ vcat, const int* __restrict__ flags)
{
  const int F = flags[1];
  const int j = blockIdx.x, lane = threadIdx.x;
  if (j >= 1028) { if (lane == 0) vcat[j] = 0.0f; return; }
  const int Kj = (j >= 512 && j < 1024) ? 512 : 899;
  float s = 0.0f;
  for (int o = lane; o < Kj; o += 64) {
    float w;
    if (j < 128) w = ldx(rkW, F, (long)j * 899 + o);
    else if (j < 256) w = ldx(wkW, F, (long)(j - 128) * 899 + o);
    else if (j < 384) w = ldx(erW, F, (long)(j - 256) * 899 + o);
    else if (j < 512) w = ldx(adW, F, (long)(j - 384) * 899 + o);
    else if (j < 1024) w = ldx(pW, F, (long)(j - 512) * 512 + o);
    else {
      const void* sp = (j == 1024) ? rbW : (j == 1025) ? rgW
                     : (j == 1026) ? wbW : wgW;
      w = ldx(sp, F, o);
    }
    s += w * ldx(bout, F, o);
  }
  #pragma unroll
  for (int off = 32; off > 0; off >>= 1) s += __shfl_down(s, off);
  if (lane == 0) {
    float b;
    if (j < 128) b = ldx(rkb, F, j);
    else if (j < 256) b = ldx(wkb, F, j - 128);
    else if (j < 384) b = ldx(erb, F, j - 256);
    else if (j < 512) b = ldx(adb, F, j - 384);
    else if (j < 1024) b = ldx(pb, F, j - 512);
    else if (j == 1024) b = ldx(rbb, F, 0);
    else if (j == 1025) b = ldx(rgb, F, 0);
    else if (j == 1026) b = ldx(wbb, F, 0);
    else b = ldx(wgb, F, 0);
    vcat[j] = s + b;
  }
}

extern "C" void kernel_launch(void* const* d_in, const int* in_sizes, int n_in,
                              void* d_out, int out_size, void* d_ws, size_t ws_size,
                              hipStream_t stream) {
  const void* x      = d_in[0];
  const void* memory = d_in[1];
  const void* Wih    = d_in[2];
  const void* Whh    = d_in[3];
  const void* bih    = d_in[4];
  const void* bhh    = d_in[5];
  const void* Wout   = d_in[6];
  const void* bout   = d_in[7];
  const void* rkW    = d_in[8];
  const void* rkb    = d_in[9];
  const void* rbW    = d_in[10];
  const void* rbb    = d_in[11];
  const void* rgW    = d_in[12];
  const void* rgb    = d_in[13];
  const void* wkW    = d_in[14];
  const void* wkb    = d_in[15];
  const void* wbW    = d_in[16];
  const void* wbb    = d_in[17];
  const void* wgW    = d_in[18];
  const void* wgb    = d_in[19];
  const void* erW    = d_in[20];
  const void* erb    = d_in[21];
  const void* adW    = d_in[22];
  const void* adb    = d_in[23];
  const void* pW     = d_in[24];
  const void* pb     = d_in[25];

  char* p = (char*)d_ws;
  auto alloc = [&](size_t bytes) -> char* {
    char* r = p; p += (bytes + 255) & ~(size_t)255; return r;
  };
  // big holds (in time sequence): [init] Wcat+WoutT | [loop] Csim -> Cea -> rv partials
  char*           big    = alloc(256L * 16384 * 2);          // 8.4 MB
  unsigned short* Wcat   = (unsigned short*)big;             // 1152*960*2 = 2.21 MB
  unsigned short* WoutT  = (unsigned short*)(big + 2359296); // 1024*960*2 = 1.97 MB
  unsigned short* W_lstm = (unsigned short*)alloc(4096L * 1664 * 2);
  unsigned short* Wcomb  = (unsigned short*)alloc(1152L * 1024 * 2);
  float*          vcat   = (float*)alloc(1152L * 4);
  float*          bsum   = (float*)alloc(4096L * 4);
  unsigned short* x_bf   = (unsigned short*)alloc(32L * 128 * 512 * 2);
  unsigned short* ci_h   = (unsigned short*)alloc(128L * 1664 * 2);
  float*          Cg     = (float*)alloc(128L * 4096 * 4);
  float*          c      = (float*)alloc(128L * 1024 * 4);
  unsigned short* keys_n = (unsigned short*)alloc(256L * 128 * 2);
  unsigned short* EA     = (unsigned short*)alloc(256L * 128 * 2);
  float*          sc     = (float*)alloc(4L * 128 * 4);
  float*          rw     = (float*)alloc(128L * 16384 * 4);
  unsigned short* ww_nat = (unsigned short*)alloc(128L * 16384 * 2);
  unsigned short* ww_t   = (unsigned short*)alloc(16384L * 128 * 2);
  float*          mem    = (float*)alloc(16384L * 128 * 4);
  unsigned short* memn   = (unsigned short*)alloc(16384L * 128 * 2);
  unsigned short* mem_t  = (unsigned short*)alloc(128L * 16384 * 2);
  int*            flags  = (int*)alloc(256);

  probe_dtype<<<1, 64, 0, stream>>>((const unsigned int*)Whh, flags);
  probe_layout<<<1, 64, 0, stream>>>(flags);
  init_pack<<<8192, 256, 0, stream>>>(x, Wih, Whh, bih, bhh, rkW, wkW, erW, adW,
                                      pW, rbW, rgW, wbW, wgW, W_lstm, bsum, x_bf,
                                      Wcat, ci_h, c, rw, flags);
  init_mem<<<256, 256, 0, stream>>>(memory, mem, memn, mem_t, flags);
  transpose_wout<<<dim3(16, 15, 1), 256, 0, stream>>>(Wout, WoutT, flags);
  init_vcat<<<1152, 64, 0, stream>>>(rkW, wkW, erW, adW, pW, rbW, rgW, wbW, wgW,
                                     bout, rkb, wkb, erb, adb, pb, rbb, rgb,
                                     wbb, wgb, vcat, flags);
  // Wcomb[1152,1024] = Wcat[1152,960] @ WoutT[1024,960]^T   (bf16 out)
  gemm_pipe<128, 64, 2, 0><<<dim3(9, 16, 1), 256, 0, stream>>>(
      Wcat, 960, WoutT, 960, 960, 1152, 1024, nullptr, 1024, Wcomb, flags);

  for (int t = 0; t < 32; ++t) {
    // Cg[128,4096] = ci_h[128,1664] @ W_lstm^T
    gemm_pipe<128, 64, 0, 0><<<dim3(1, 64, 1), 256, 0, stream>>>(
        ci_h, 1664, W_lstm, 1664, 1664, 128, 4096, Cg, 4096, nullptr, flags);
    lstm_ew<<<768, 256, 0, stream>>>(Cg, bsum, c, ci_h, x_bf, t);
    // heads: keys_n, EA, sc, d_out
    gemm_heads<<<dim3(9, 2, 1), 256, 0, stream>>>(
        Wcomb, ci_h + 640, 1664, vcat, keys_n, EA, sc, d_out, t, flags);
    // Csim[256,16384] = keys_n[256,128] @ memn[16384,128]^T -> big (bf16)
    gemm_pipe<128, 64, 2, 0><<<dim3(2, 256, 1), 256, 0, stream>>>(
        keys_n, 128, memn, 128, 128, 256, 16384, nullptr, 16384,
        (unsigned short*)big, flags);
    softmax_interp<<<256, 256, 0, stream>>>((const unsigned short*)big, sc, rw, ww_nat);
    transpose_ww<<<dim3(256, 2, 1), 256, 0, stream>>>(ww_nat, ww_t);
    // Cea[16384,256] = ww_t[16384,128] @ EA[256,128]^T -> big (bf16)
    gemm_pipe<128, 64, 2, 0><<<dim3(128, 4, 1), 256, 0, stream>>>(
        ww_t, 128, EA, 128, 128, 16384, 256, nullptr, 256,
        (unsigned short*)big, flags);
    mem_update<<<256, 256, 0, stream>>>((const unsigned short*)big, mem, memn, mem_t);
    // rv partials: rw[128,16384](fp32) @ mem_t[128,16384]^T, split-K 64 -> big
    gemm_pipe<128, 64, 3, 1><<<dim3(1, 2, 64), 256, 0, stream>>>(
        rw, 16384, mem_t, 16384, 256, 128, 128, (float*)big, 128, nullptr, flags);
    rv_reduce<<<64, 256, 0, stream>>>((const float*)big, ci_h);
  }
}

// Round 5
// 2885.974 us; speedup vs baseline: 4.2284x; 1.4303x over previous
//
#include <hip/hip_runtime.h>

typedef __attribute__((ext_vector_type(8))) short bf16x8;
typedef __attribute__((ext_vector_type(4))) float f32x4;

__device__ __forceinline__ float bf2f(unsigned short u) {
  union { float f; unsigned int i; } v; v.i = ((unsigned int)u) << 16; return v.f;
}
__device__ __forceinline__ unsigned short f2bf(float f) {
  union { float f; unsigned int i; } v; v.f = f;
  unsigned int r = v.i + 0x7fffu + ((v.i >> 16) & 1u);
  return (unsigned short)(r >> 16);
}
__device__ __forceinline__ float sigf(float x) { return 1.0f / (1.0f + expf(-x)); }
__device__ __forceinline__ float softplusf(float x) {
  return (x > 20.0f) ? x : log1pf(expf(x));
}
// NaN firewall: fmaxf(NaN,-1e6) = -1e6 => outputs provably finite
__device__ __forceinline__ float sat(float v) {
  return fminf(fmaxf(v, -1.0e6f), 1.0e6f);
}
__device__ __forceinline__ float ldx(const void* p, int is32, long i) {
  return is32 ? ((const float*)p)[i] : bf2f(((const unsigned short*)p)[i]);
}
template<int A32>
__device__ __forceinline__ bf16x8 load8(const void* base, long off) {
  if (A32) {
    const float* p = (const float*)base + off;
    f32x4 a = *(const f32x4*)p;
    f32x4 b = *(const f32x4*)(p + 4);
    bf16x8 r;
    r[0] = (short)f2bf(a[0]); r[1] = (short)f2bf(a[1]);
    r[2] = (short)f2bf(a[2]); r[3] = (short)f2bf(a[3]);
    r[4] = (short)f2bf(b[0]); r[5] = (short)f2bf(b[1]);
    r[6] = (short)f2bf(b[2]); r[7] = (short)f2bf(b[3]);
    return r;
  }
  return *(const bf16x8*)((const unsigned short*)base + off);
}

// flags[0] = C/D layout swap, flags[1] = input dtype (0=bf16, 1=fp32)

__global__ __launch_bounds__(64) void probe_dtype(
    const unsigned int* __restrict__ w, int* __restrict__ flags)
{
  const int lane = threadIdx.x;
  int cnt = 0;
  for (int i = 0; i < 16; ++i) {
    unsigned int word = w[lane * 16 + i];
    float av = fabsf(bf2f((unsigned short)(word & 0xFFFFu)));
    if (av > 1.0e-4f && av < 1.0f) cnt++;
  }
  #pragma unroll
  for (int off = 32; off > 0; off >>= 1) cnt += __shfl_xor(cnt, off);
  if (lane == 0) flags[1] = (cnt > 512) ? 0 : 1;
}

__global__ __launch_bounds__(64) void probe_layout(int* __restrict__ flags) {
  const int lane = threadIdx.x;
  const int qr = lane & 15, quad = lane >> 4;
  bf16x8 a, b;
  #pragma unroll
  for (int j = 0; j < 8; ++j) {
    int k = quad * 8 + j;
    a[j] = (short)f2bf((k == qr) ? 1.0f : 0.0f);
    b[j] = (short)f2bf((float)(k + 1));
  }
  f32x4 acc = {0.0f, 0.0f, 0.0f, 0.0f};
  acc = __builtin_amdgcn_mfma_f32_16x16x32_bf16(a, b, acc, 0, 0, 0);
  bool ok0 = true, ok1 = true;
  #pragma unroll
  for (int rg = 0; rg < 4; ++rg) {
    ok0 = ok0 && (acc[rg] == (float)(quad * 4 + rg + 1));
    ok1 = ok1 && (acc[rg] == (float)(qr + 1));
  }
  int a0 = __all(ok0 ? 1 : 0);
  int a1 = __all(ok1 ? 1 : 0);
  if (lane == 0) flags[0] = a0 ? 0 : (a1 ? 1 : 0);
}

// ---------------------------------------------------------------------------
// Double-buffered MFMA GEMM: C[M,N] = A[M,K] * B[N,K]^T (BT=0) or
// C[M,N] = A[M,K] * B[K,N] (BT=1; requires BN=64 — transpose during staging).
// EPI 2: bf16 store. EPI 3: split-K fp32 partial. A32: A is fp32.
// ---------------------------------------------------------------------------
template<int BM, int BN, int EPI, int A32, int BT>
__global__ __launch_bounds__(256) void gemm_pipe(
    const void* __restrict__ A, int lda,
    const unsigned short* __restrict__ B, int ldb,
    int kChunk, int Mtot, int Ntot,
    float* __restrict__ C, long long ldc, unsigned short* __restrict__ Cb,
    const int* __restrict__ flags)
{
  constexpr int LDT = 72;
  constexpr int AI = BM / 32;
  constexpr int BI = BN / 32;
  __shared__ unsigned short smem[2][(BM + BN) * LDT];
  const int tid = threadIdx.x;
  const int lane = tid & 63, wid = tid >> 6;
  const int wm = wid & 1, wn = wid >> 1;
  constexpr int WM = BM / 2, WN = BN / 2;
  constexpr int TM = WM / 16, TN = WN / 16;
  const int m0 = blockIdx.x * BM, n0 = blockIdx.y * BN;
  const int kBeg = blockIdx.z * kChunk;
  const int qr = lane & 15, quad = lane >> 4;
  const int NIT = kChunk >> 6;

  f32x4 acc[TM][TN] = {};
  bf16x8 ar[AI], br[BI];

  auto loadAB = [&](int k0) {
    #pragma unroll
    for (int i = 0; i < AI; ++i) {
      int lin = i * 256 + tid; int row = lin >> 3, q = (lin & 7) << 3;
      ar[i] = load8<A32>(A, (long)(m0 + row) * lda + k0 + q);
    }
    #pragma unroll
    for (int i = 0; i < BI; ++i) {
      int lin = i * 256 + tid;
      if (BT) {
        int kl = lin >> 3, nq = (lin & 7) << 3;
        br[i] = *(const bf16x8*)(B + (long)(k0 + kl) * ldb + n0 + nq);
      } else {
        int row = lin >> 3, q = (lin & 7) << 3;
        br[i] = *(const bf16x8*)(B + (long)(n0 + row) * ldb + k0 + q);
      }
    }
  };
  auto stage = [&](int buf) {
    #pragma unroll
    for (int i = 0; i < AI; ++i) {
      int lin = i * 256 + tid; int row = lin >> 3, q = (lin & 7) << 3;
      *(bf16x8*)&smem[buf][row * LDT + q] = ar[i];
    }
    #pragma unroll
    for (int i = 0; i < BI; ++i) {
      int lin = i * 256 + tid;
      if (BT) {
        int kl = lin >> 3, nq = (lin & 7) << 3;
        #pragma unroll
        for (int j = 0; j < 8; ++j)
          smem[buf][(BM + nq + j) * LDT + kl] = (unsigned short)br[i][j];
      } else {
        int row = lin >> 3, q = (lin & 7) << 3;
        *(bf16x8*)&smem[buf][(BM + row) * LDT + q] = br[i];
      }
    }
  };

  loadAB(kBeg);
  stage(0);
  __syncthreads();
  for (int it = 0; it < NIT; ++it) {
    if (it + 1 < NIT) loadAB(kBeg + (it + 1) * 64);
    const unsigned short* As = &smem[it & 1][0];
    const unsigned short* Bs = &smem[it & 1][BM * LDT];
    #pragma unroll
    for (int ks = 0; ks < 64; ks += 32) {
      bf16x8 af[TM], bfv[TN];
      #pragma unroll
      for (int mt = 0; mt < TM; ++mt)
        af[mt] = *(const bf16x8*)&As[(wm * WM + mt * 16 + qr) * LDT + ks + quad * 8];
      #pragma unroll
      for (int nt = 0; nt < TN; ++nt)
        bfv[nt] = *(const bf16x8*)&Bs[(wn * WN + nt * 16 + qr) * LDT + ks + quad * 8];
      #pragma unroll
      for (int mt = 0; mt < TM; ++mt)
        #pragma unroll
        for (int nt = 0; nt < TN; ++nt)
          acc[mt][nt] = __builtin_amdgcn_mfma_f32_16x16x32_bf16(af[mt], bfv[nt], acc[mt][nt], 0, 0, 0);
    }
    if (it + 1 < NIT) { stage((it + 1) & 1); __syncthreads(); }
  }

  const int swap = flags[0];
  #pragma unroll
  for (int mt = 0; mt < TM; ++mt)
    #pragma unroll
    for (int nt = 0; nt < TN; ++nt)
      #pragma unroll
      for (int rg = 0; rg < 4; ++rg) {
        int ri = swap ? qr : (quad * 4 + rg);
        int ci = swap ? (quad * 4 + rg) : qr;
        int gm = m0 + wm * WM + mt * 16 + ri;
        int gn = n0 + wn * WN + nt * 16 + ci;
        float v = sat(acc[mt][nt][rg]);
        if (EPI == 2) Cb[(size_t)gm * ldc + gn] = f2bf(v);
        else C[(size_t)blockIdx.z * Mtot * Ntot + (size_t)gm * Ntot + gn] = v;
      }
}

// ---------------------------------------------------------------------------
// Gates GEMM + fused LSTM. A = ci_h_cur [128][1664]; B = W_lstm2 [4096][1664]
// with rows reordered r' = j*4+gate. grid (2,64): x = batch half, y = 16-j tile.
// Epilogue: tile -> LDS -> c/h update; h written to ci_h_next; xt(t+1) staged.
// ---------------------------------------------------------------------------
__global__ __launch_bounds__(256) void gemm_gates(
    const unsigned short* __restrict__ A, const unsigned short* __restrict__ B,
    const float* __restrict__ bsum2, float* __restrict__ c,
    unsigned short* __restrict__ nxt, const unsigned short* __restrict__ x_bf,
    int t, const int* __restrict__ flags)
{
  constexpr int LDT = 72;
  __shared__ unsigned short smem[2][128 * LDT];
  __shared__ float Ssc[64][65];
  const int tid = threadIdx.x;
  const int lane = tid & 63, wid = tid >> 6;
  const int wm = wid & 1, wn = wid >> 1;
  const int m0 = blockIdx.x * 64, n0 = blockIdx.y * 64;
  const int qr = lane & 15, quad = lane >> 4;
  const int NIT = 26;  // K = 1664

  f32x4 acc[2][2] = {};
  bf16x8 ar[2], br[2];
  auto loadAB = [&](int k0) {
    #pragma unroll
    for (int i = 0; i < 2; ++i) {
      int lin = i * 256 + tid; int row = lin >> 3, q = (lin & 7) << 3;
      ar[i] = *(const bf16x8*)(A + (long)(m0 + row) * 1664 + k0 + q);
      br[i] = *(const bf16x8*)(B + (long)(n0 + row) * 1664 + k0 + q);
    }
  };
  auto stage = [&](int buf) {
    #pragma unroll
    for (int i = 0; i < 2; ++i) {
      int lin = i * 256 + tid; int row = lin >> 3, q = (lin & 7) << 3;
      *(bf16x8*)&smem[buf][row * LDT + q] = ar[i];
      *(bf16x8*)&smem[buf][(64 + row) * LDT + q] = br[i];
    }
  };
  loadAB(0); stage(0); __syncthreads();
  for (int it = 0; it < NIT; ++it) {
    if (it + 1 < NIT) loadAB((it + 1) * 64);
    const unsigned short* As = &smem[it & 1][0];
    const unsigned short* Bs = &smem[it & 1][64 * LDT];
    #pragma unroll
    for (int ks = 0; ks < 64; ks += 32) {
      bf16x8 af[2], bfv[2];
      #pragma unroll
      for (int mt = 0; mt < 2; ++mt)
        af[mt] = *(const bf16x8*)&As[(wm * 32 + mt * 16 + qr) * LDT + ks + quad * 8];
      #pragma unroll
      for (int nt = 0; nt < 2; ++nt)
        bfv[nt] = *(const bf16x8*)&Bs[(wn * 32 + nt * 16 + qr) * LDT + ks + quad * 8];
      #pragma unroll
      for (int mt = 0; mt < 2; ++mt)
        #pragma unroll
        for (int nt = 0; nt < 2; ++nt)
          acc[mt][nt] = __builtin_amdgcn_mfma_f32_16x16x32_bf16(af[mt], bfv[nt], acc[mt][nt], 0, 0, 0);
    }
    if (it + 1 < NIT) { stage((it + 1) & 1); __syncthreads(); }
  }

  const int swap = flags[0];
  // dump: Ssc[gate-row local][batch local]
  #pragma unroll
  for (int mt = 0; mt < 2; ++mt)
    #pragma unroll
    for (int nt = 0; nt < 2; ++nt)
      #pragma unroll
      for (int rg = 0; rg < 4; ++rg) {
        int ri = swap ? qr : (quad * 4 + rg);
        int ci = swap ? (quad * 4 + rg) : qr;
        Ssc[wn * 32 + nt * 16 + ci][wm * 32 + mt * 16 + ri] = acc[mt][nt][rg];
      }
  __syncthreads();
  {
    const int jl = tid & 15, bh = tid >> 4;
    const int jg = (n0 >> 2) + jl;
    const float b0 = bsum2[n0 + jl * 4 + 0];
    const float b1 = bsum2[n0 + jl * 4 + 1];
    const float b2 = bsum2[n0 + jl * 4 + 2];
    const float b3 = bsum2[n0 + jl * 4 + 3];
    #pragma unroll
    for (int p = 0; p < 4; ++p) {
      int bl = bh + p * 16;
      int bb = m0 + bl;
      float gi_ = Ssc[jl * 4 + 0][bl] + b0;
      float gf  = Ssc[jl * 4 + 1][bl] + b1;
      float gg  = Ssc[jl * 4 + 2][bl] + b2;
      float go  = Ssc[jl * 4 + 3][bl] + b3;
      size_t cix = (size_t)bb * 1024 + jg;
      float cn = sat(sigf(gf) * c[cix] + sigf(gi_) * tanhf(gg));
      c[cix] = cn;
      nxt[bb * 1664 + 640 + jg] = f2bf(sigf(go) * tanhf(cn));
    }
  }
  if (t + 1 < 32) {
    int blk = blockIdx.y * 2 + blockIdx.x;
    #pragma unroll
    for (int i = 0; i < 2; ++i) {
      int e = blk * 512 + i * 256 + tid;
      nxt[(e >> 9) * 1664 + (e & 511)] = x_bf[(size_t)(t + 1) * 65536 + e];
    }
  }
}

// ---------------------------------------------------------------------------
// Heads mega-GEMM: H[1152,128] = Wcomb[1152,1024] @ h[128,1024]^T (+vcat).
// EA interleaved: row j' = 2w+e (e: 0=erase sigmoid, 1=add tanh).
// ---------------------------------------------------------------------------
__global__ __launch_bounds__(256) void gemm_heads(
    const unsigned short* __restrict__ Wcomb,
    const unsigned short* __restrict__ h, int ldb,
    const float* __restrict__ vcat,
    unsigned short* __restrict__ keys_n, unsigned short* __restrict__ EA,
    float* __restrict__ sc, void* __restrict__ outp, int t,
    const int* __restrict__ flags)
{
  constexpr int BM = 128, BN = 64, LDT = 72;
  __shared__ unsigned short smem[2][(BM + BN) * LDT];
  __shared__ float colss[64];
  __shared__ float cinv[64];
  const int tid = threadIdx.x;
  const int lane = tid & 63, wid = tid >> 6;
  const int wm = wid & 1, wn = wid >> 1;
  constexpr int TM = 4, TN = 2;
  const int m0 = blockIdx.x * BM, n0 = blockIdx.y * BN;
  const int qr = lane & 15, quad = lane >> 4;
  const int NIT = 16;  // K = 1024

  f32x4 acc[TM][TN] = {};
  bf16x8 ar[4], br[2];
  auto loadAB = [&](int k0) {
    #pragma unroll
    for (int i = 0; i < 4; ++i) {
      int lin = i * 256 + tid; int row = lin >> 3, q = (lin & 7) << 3;
      ar[i] = *(const bf16x8*)(Wcomb + (long)(m0 + row) * 1024 + k0 + q);
    }
    #pragma unroll
    for (int i = 0; i < 2; ++i) {
      int lin = i * 256 + tid; int row = lin >> 3, q = (lin & 7) << 3;
      br[i] = *(const bf16x8*)(h + (long)(n0 + row) * ldb + k0 + q);
    }
  };
  auto stage = [&](int buf) {
    #pragma unroll
    for (int i = 0; i < 4; ++i) {
      int lin = i * 256 + tid; int row = lin >> 3, q = (lin & 7) << 3;
      *(bf16x8*)&smem[buf][row * LDT + q] = ar[i];
    }
    #pragma unroll
    for (int i = 0; i < 2; ++i) {
      int lin = i * 256 + tid; int row = lin >> 3, q = (lin & 7) << 3;
      *(bf16x8*)&smem[buf][(BM + row) * LDT + q] = br[i];
    }
  };

  loadAB(0);
  stage(0);
  __syncthreads();
  for (int it = 0; it < NIT; ++it) {
    if (it + 1 < NIT) loadAB((it + 1) * 64);
    const unsigned short* As = &smem[it & 1][0];
    const unsigned short* Bs = &smem[it & 1][BM * LDT];
    #pragma unroll
    for (int ks = 0; ks < 64; ks += 32) {
      bf16x8 af[TM], bfv[TN];
      #pragma unroll
      for (int mt = 0; mt < TM; ++mt)
        af[mt] = *(const bf16x8*)&smem[it & 1][(wm * 64 + mt * 16 + qr) * LDT + ks + quad * 8];
      #pragma unroll
      for (int nt = 0; nt < TN; ++nt)
        bfv[nt] = *(const bf16x8*)&Bs[(wn * 32 + nt * 16 + qr) * LDT + ks + quad * 8];
      (void)As;
      #pragma unroll
      for (int mt = 0; mt < TM; ++mt)
        #pragma unroll
        for (int nt = 0; nt < TN; ++nt)
          acc[mt][nt] = __builtin_amdgcn_mfma_f32_16x16x32_bf16(af[mt], bfv[nt], acc[mt][nt], 0, 0, 0);
    }
    if (it + 1 < NIT) { stage((it + 1) & 1); __syncthreads(); }
  }

  const int swap = flags[0];
  const int F = flags[1];
  #pragma unroll
  for (int mt = 0; mt < TM; ++mt)
    #pragma unroll
    for (int nt = 0; nt < TN; ++nt)
      #pragma unroll
      for (int rg = 0; rg < 4; ++rg) {
        int ri = swap ? qr : (quad * 4 + rg);
        int gm = m0 + wm * 64 + mt * 16 + ri;
        acc[mt][nt][rg] = sat(acc[mt][nt][rg] + vcat[gm]);
      }

  if (m0 < 256) {
    if (tid < 64) colss[tid] = 0.0f;
    __syncthreads();
    #pragma unroll
    for (int nt = 0; nt < TN; ++nt)
      #pragma unroll
      for (int rg = 0; rg < 4; ++rg) {
        float part = 0.0f;
        #pragma unroll
        for (int mt = 0; mt < TM; ++mt) {
          float v = acc[mt][nt][rg]; part += v * v;
        }
        int ci = swap ? (quad * 4 + rg) : qr;
        atomicAdd(&colss[wn * 32 + nt * 16 + ci], part);
      }
    __syncthreads();
    if (tid < 64) cinv[tid] = 1.0f / fmaxf(sqrtf(colss[tid]), 1e-12f);
    __syncthreads();
    const int head = m0 >> 7;
    #pragma unroll
    for (int mt = 0; mt < TM; ++mt)
      #pragma unroll
      for (int nt = 0; nt < TN; ++nt)
        #pragma unroll
        for (int rg = 0; rg < 4; ++rg) {
          int ri = swap ? qr : (quad * 4 + rg);
          int ci = swap ? (quad * 4 + rg) : qr;
          int w = wm * 64 + mt * 16 + ri;
          int cl = wn * 32 + nt * 16 + ci;
          keys_n[(size_t)(head * 128 + n0 + cl) * 128 + w] =
              f2bf(acc[mt][nt][rg] * cinv[cl]);
        }
  } else {
    #pragma unroll
    for (int mt = 0; mt < TM; ++mt)
      #pragma unroll
      for (int nt = 0; nt < TN; ++nt)
        #pragma unroll
        for (int rg = 0; rg < 4; ++rg) {
          int ri = swap ? qr : (quad * 4 + rg);
          int ci = swap ? (quad * 4 + rg) : qr;
          int gm = m0 + wm * 64 + mt * 16 + ri;
          int gn = n0 + wn * 32 + nt * 16 + ci;
          float v = acc[mt][nt][rg];
          if (m0 == 256) {
            EA[(size_t)((gm - 256) * 2) * 128 + gn] = f2bf(sigf(v));
          } else if (m0 == 384) {
            EA[(size_t)((gm - 384) * 2 + 1) * 128 + gn] = f2bf(tanhf(v));
          } else if (m0 < 1024) {
            int o = gm - 512;
            size_t idx = (size_t)gn * 16384 + (size_t)t * 512 + o;
            if (F) ((float*)outp)[idx] = v;
            else ((unsigned short*)outp)[idx] = f2bf(v);
          } else if (gm < 1028) {
            float sp = fminf(softplusf(v), 1.0e4f);
            int j = gm - 1024;
            sc[j * 128 + gn] = (j & 1) ? (1.0f + sp) : sp;
          }
        }
  }
}

// ---------------------------------------------------------------------------
// Single-pass softmax + interpolation. Row cached in 64 VGPRs.
// ---------------------------------------------------------------------------
__global__ __launch_bounds__(256) void softmax1(
    const unsigned short* __restrict__ Csim, const float* __restrict__ sc,
    float* __restrict__ rw, unsigned short* __restrict__ ww)
{
  const int r = blockIdx.x, tid = threadIdx.x;
  const int b = r & 127;
  const bool isRead = r < 128;
  const float beta  = isRead ? sc[b]       : sc[256 + b];
  const float gamma = isRead ? sc[128 + b] : sc[384 + b];
  const unsigned short* row = Csim + (size_t)r * 16384;
  __shared__ float red[4];
  float v[64];
  #pragma unroll
  for (int p = 0; p < 8; ++p) {
    bf16x8 x = *(const bf16x8*)(row + p * 2048 + tid * 8);
    #pragma unroll
    for (int j = 0; j < 8; ++j) v[p * 8 + j] = bf2f((unsigned short)x[j]);
  }
  float mx = -3.0e38f;
  #pragma unroll
  for (int p = 0; p < 64; ++p) mx = fmaxf(mx, v[p]);
  #pragma unroll
  for (int off = 32; off > 0; off >>= 1) mx = fmaxf(mx, __shfl_xor(mx, off));
  if ((tid & 63) == 0) red[tid >> 6] = mx;
  __syncthreads();
  mx = fmaxf(fmaxf(red[0], red[1]), fmaxf(red[2], red[3]));
  const float m = beta * mx;
  __syncthreads();
  float s = 0.0f;
  #pragma unroll
  for (int p = 0; p < 64; ++p) { v[p] = expf(beta * v[p] - m); s += v[p]; }
  #pragma unroll
  for (int off = 32; off > 0; off >>= 1) s += __shfl_xor(s, off);
  if ((tid & 63) == 0) red[tid >> 6] = s;
  __syncthreads();
  s = red[0] + red[1] + red[2] + red[3];
  const float inv = 1.0f / fmaxf(s, 1e-30f);
  if (isRead) {
    float* prow = rw + (size_t)b * 16384;
    #pragma unroll
    for (int p = 0; p < 8; ++p) {
      long base = p * 2048 + tid * 8;
      f32x4 o0 = *(const f32x4*)(prow + base);
      f32x4 o1 = *(const f32x4*)(prow + base + 4);
      #pragma unroll
      for (int j = 0; j < 4; ++j) {
        o0[j] = sat(gamma * v[p * 8 + j] * inv + (1.0f - gamma) * o0[j]);
        o1[j] = sat(gamma * v[p * 8 + 4 + j] * inv + (1.0f - gamma) * o1[j]);
      }
      *(f32x4*)(prow + base) = o0;
      *(f32x4*)(prow + base + 4) = o1;
    }
  } else {
    unsigned short* wrow = ww + (size_t)b * 16384;
    const float u = 1.0f / 16384.0f;
    #pragma unroll
    for (int p = 0; p < 8; ++p) {
      long base = p * 2048 + tid * 8;
      bf16x8 o;
      #pragma unroll
      for (int j = 0; j < 8; ++j)
        o[j] = (short)f2bf(sat(gamma * v[p * 8 + j] * inv + (1.0f - gamma) * u));
      *(bf16x8*)(wrow + base) = o;
    }
  }
}

// ---------------------------------------------------------------------------
// write_mem: er/ad GEMM + memory update fused. Per block: 64 mem rows.
// C[64 n][256 j'] = ww[K=128 b][n]^T(AT) @ EA[256 j'][128 b]^T, then
// mem = sat(mem*(1-er)+ad); writes mem fp32, memn (row-normalized), mem_bf.
// ---------------------------------------------------------------------------
__global__ __launch_bounds__(256) void write_mem(
    const unsigned short* __restrict__ ww, const unsigned short* __restrict__ EA,
    float* __restrict__ mem, unsigned short* __restrict__ memn,
    unsigned short* __restrict__ mem_bf, const int* __restrict__ flags)
{
  constexpr int LDT = 72;
  __shared__ unsigned short smem[320 * LDT];   // As 64 rows | Bs 256 rows; Sea reuse
  const int tid = threadIdx.x;
  const int lane = tid & 63, wid = tid >> 6;
  const int qr = lane & 15, quad = lane >> 4;
  const int n0 = blockIdx.x * 64;
  f32x4 acc[4][4] = {};
  bf16x8 pa[2], pb[8];

  // prefetch kk into regs
  auto loadRegs = [&](int kk) {
    #pragma unroll
    for (int i = 0; i < 2; ++i) {
      int ch = i * 256 + tid; int bl = ch >> 3, nq = (ch & 7) << 3;
      pa[i] = *(const bf16x8*)(ww + (size_t)(kk * 64 + bl) * 16384 + n0 + nq);
    }
    #pragma unroll
    for (int i = 0; i < 8; ++i) {
      int ch = i * 256 + tid; int j = ch >> 3, q = (ch & 7) << 3;
      pb[i] = *(const bf16x8*)(EA + (size_t)j * 128 + kk * 64 + q);
    }
  };
  auto stageRegs = [&]() {
    #pragma unroll
    for (int i = 0; i < 2; ++i) {
      int ch = i * 256 + tid; int bl = ch >> 3, nq = (ch & 7) << 3;
      #pragma unroll
      for (int j = 0; j < 8; ++j)
        smem[(nq + j) * LDT + bl] = (unsigned short)pa[i][j];
    }
    #pragma unroll
    for (int i = 0; i < 8; ++i) {
      int ch = i * 256 + tid; int j = ch >> 3, q = (ch & 7) << 3;
      *(bf16x8*)&smem[(64 + j) * LDT + q] = pb[i];
    }
  };
  auto doMfma = [&]() {
    #pragma unroll
    for (int ks = 0; ks < 64; ks += 32) {
      bf16x8 af[4], bfv[4];
      #pragma unroll
      for (int mt = 0; mt < 4; ++mt)
        af[mt] = *(const bf16x8*)&smem[(mt * 16 + qr) * LDT + ks + quad * 8];
      #pragma unroll
      for (int nt = 0; nt < 4; ++nt)
        bfv[nt] = *(const bf16x8*)&smem[(64 + wid * 64 + nt * 16 + qr) * LDT + ks + quad * 8];
      #pragma unroll
      for (int mt = 0; mt < 4; ++mt)
        #pragma unroll
        for (int nt = 0; nt < 4; ++nt)
          acc[mt][nt] = __builtin_amdgcn_mfma_f32_16x16x32_bf16(af[mt], bfv[nt], acc[mt][nt], 0, 0, 0);
    }
  };

  loadRegs(0);
  stageRegs();
  loadRegs(1);
  __syncthreads();
  doMfma();
  __syncthreads();
  stageRegs();
  __syncthreads();
  doMfma();
  __syncthreads();   // all LDS reads done; reuse smem as Sea [64][264]

  const int swap = flags[0];
  #pragma unroll
  for (int mt = 0; mt < 4; ++mt)
    #pragma unroll
    for (int nt = 0; nt < 4; ++nt)
      #pragma unroll
      for (int rg = 0; rg < 4; ++rg) {
        int ri = swap ? qr : (quad * 4 + rg);
        int ci = swap ? (quad * 4 + rg) : qr;
        int nl = mt * 16 + ri;
        int j  = wid * 64 + nt * 16 + ci;
        smem[nl * 264 + j] = f2bf(sat(acc[mt][nt][rg]));
      }
  __syncthreads();
  {
    const int nl = tid >> 2, ws = (tid & 3) << 5;
    const unsigned int* Srow = (const unsigned int*)&smem[nl * 264];
    const size_t gbase = (size_t)(n0 + nl) * 128 + ws;
    float nv[32];
    float ss = 0.0f;
    #pragma unroll
    for (int i = 0; i < 32; ++i) {
      unsigned int pr = Srow[ws + i];
      float er = bf2f((unsigned short)(pr & 0xFFFFu));
      float ad = bf2f((unsigned short)(pr >> 16));
      float x = sat(mem[gbase + i] * (1.0f - er) + ad);
      nv[i] = x;
      ss += x * x;
    }
    ss += __shfl_xor(ss, 1);
    ss += __shfl_xor(ss, 2);
    const float inv = 1.0f / fmaxf(sqrtf(ss), 1e-12f);
    #pragma unroll
    for (int i = 0; i < 32; ++i) {
      mem[gbase + i] = nv[i];
      memn[gbase + i] = f2bf(nv[i] * inv);
      mem_bf[gbase + i] = f2bf(nv[i]);
    }
  }
}

__global__ __launch_bounds__(256) void init_mem(
    const void* __restrict__ memory, float* __restrict__ mem,
    unsigned short* __restrict__ memn, unsigned short* __restrict__ mem_bf,
    const int* __restrict__ flags)
{
  const int F = flags[1];
  __shared__ float tile[64][129];
  __shared__ float inv[64];
  const int n0 = blockIdx.x * 64, tid = threadIdx.x;
  for (int e = tid; e < 8192; e += 256) {
    int r = e >> 7, w = e & 127;
    size_t gi = (size_t)(n0 + r) * 128 + w;
    float nv = ldx(memory, F, (long)gi);
    mem[gi] = nv;
    tile[r][w] = nv;
  }
  __syncthreads();
  if (tid < 64) {
    float ss = 0.0f;
    for (int w = 0; w < 128; ++w) { float v = tile[tid][w]; ss += v * v; }
    inv[tid] = 1.0f / fmaxf(sqrtf(ss), 1e-12f);
  }
  __syncthreads();
  for (int e = tid; e < 8192; e += 256) {
    int r = e >> 7, w = e & 127;
    size_t gi = (size_t)(n0 + r) * 128 + w;
    memn[gi] = f2bf(tile[r][w] * inv[r]);
    mem_bf[gi] = f2bf(tile[r][w]);
  }
}

__global__ __launch_bounds__(256) void rv_reduce(
    const float* __restrict__ part, unsigned short* __restrict__ nxt)
{
  int e = blockIdx.x * 256 + threadIdx.x;   // 16384
  float s = 0.0f;
  for (int z = 0; z < 64; ++z) s += part[(size_t)z * 16384 + e];
  int b = e >> 7, w = e & 127;
  nxt[b * 1664 + 512 + w] = f2bf(sat(s));
}

// ---------------------------------------------------------------------------
// Big init: W_lstm2 (rows j*4+g), bsum2, x_bf, Wcat, ci_hA, c, rw.
// ---------------------------------------------------------------------------
__global__ void init_pack(
    const void* __restrict__ x, const void* __restrict__ Wih,
    const void* __restrict__ Whh, const void* __restrict__ bih,
    const void* __restrict__ bhh,
    const void* __restrict__ rkW, const void* __restrict__ wkW,
    const void* __restrict__ erW, const void* __restrict__ adW,
    const void* __restrict__ pW,
    const void* __restrict__ rbW, const void* __restrict__ rgW,
    const void* __restrict__ wbW, const void* __restrict__ wgW,
    unsigned short* __restrict__ W_lstm, float* __restrict__ bsum,
    unsigned short* __restrict__ x_bf, unsigned short* __restrict__ Wcat,
    unsigned short* __restrict__ ci_h, float* __restrict__ c,
    float* __restrict__ rw, const int* __restrict__ flags)
{
  const int F = flags[1];
  const long T0 = 4096L * 1664;
  const long T1 = 4096;
  const long T2 = 32L * 128 * 512;
  const long T3 = 1152L * 960;
  const long T4 = 128L * 1664;
  const long T5 = 128L * 1024;
  const long T6 = 128L * 16384;
  const long total = T0 + T1 + T2 + T3 + T4 + T5 + T6;
  for (long e = (long)blockIdx.x * 256 + threadIdx.x; e < total;
       e += (long)gridDim.x * 256) {
    long r = e;
    if (r < T0) {
      int jp = (int)(r / 1664), k = (int)(r % 1664);
      int orow = (jp & 3) * 1024 + (jp >> 2);
      float v = (k < 640) ? ldx(Wih, F, (long)orow * 640 + k)
                          : ldx(Whh, F, (long)orow * 1024 + (k - 640));
      W_lstm[r] = f2bf(v);
      continue;
    }
    r -= T0;
    if (r < T1) {
      long o = (long)(r & 3) * 1024 + (r >> 2);
      bsum[r] = ldx(bih, F, o) + ldx(bhh, F, o);
      continue;
    }
    r -= T1;
    if (r < T2) {
      int t = (int)(r >> 16); long rr = r & 65535;
      int b = (int)(rr >> 9), k = (int)(rr & 511);
      x_bf[r] = f2bf(ldx(x, F, (long)b * 16384 + (long)t * 512 + k));
      continue;
    }
    r -= T2;
    if (r < T3) {
      int j = (int)(r / 960), o = (int)(r % 960);
      float v = 0.0f;
      if (j < 512) {
        if (o < 899) {
          if (j < 128) v = ldx(rkW, F, (long)j * 899 + o);
          else if (j < 256) v = ldx(wkW, F, (long)(j - 128) * 899 + o);
          else if (j < 384) v = ldx(erW, F, (long)(j - 256) * 899 + o);
          else v = ldx(adW, F, (long)(j - 384) * 899 + o);
        }
      } else if (j < 1024) {
        if (o < 512) v = ldx(pW, F, (long)(j - 512) * 512 + o);
      } else if (j < 1028) {
        if (o < 899) {
          const void* s = (j == 1024) ? rbW : (j == 1025) ? rgW
                        : (j == 1026) ? wbW : wgW;
          v = ldx(s, F, o);
        }
      }
      Wcat[r] = f2bf(v);
      continue;
    }
    r -= T3;
    if (r < T4) {
      int b = (int)(r / 1664), k = (int)(r % 1664);
      ci_h[r] = (k < 512) ? f2bf(ldx(x, F, (long)b * 16384 + k)) : (unsigned short)0;
      continue;
    }
    r -= T4;
    if (r < T5) { c[r] = 0.0f; continue; }
    r -= T5;
    rw[r] = 1.0f / 16384.0f;
  }
}

__global__ __launch_bounds__(256) void transpose_wout(
    const void* __restrict__ Wout, unsigned short* __restrict__ WoutT,
    const int* __restrict__ flags)
{
  const int F = flags[1];
  __shared__ float tile[64][65];
  const int n0 = blockIdx.x * 64, o0 = blockIdx.y * 64;
  for (int e = threadIdx.x; e < 4096; e += 256) {
    int ro = e >> 6, cn = e & 63;
    int o = o0 + ro;
    tile[ro][cn] = (o < 899) ? ldx(Wout, F, (long)o * 1024 + n0 + cn) : 0.0f;
  }
  __syncthreads();
  for (int e = threadIdx.x; e < 4096; e += 256) {
    int rn = e >> 6, co = e & 63;
    WoutT[(size_t)(n0 + rn) * 960 + o0 + co] = f2bf(tile[co][rn]);
  }
}

__global__ __launch_bounds__(64) void init_vcat(
    const void* __restrict__ rkW, const void* __restrict__ wkW,
    const void* __restrict__ erW, const void* __restrict__ adW,
    const void* __restrict__ pW,
    const void* __restrict__ rbW, const void* __restrict__ rgW,
    const void* __restrict__ wbW, const void* __restrict__ wgW,
    const void* __restrict__ bout,
    const void* __restrict__ rkb, const void* __restrict__ wkb,
    const void* __restrict__ erb, const void* __restrict__ adb,
    const void* __restrict__ pb,
    const void* __restrict__ rbb, const void* __restrict__ rgb,
    const void* __restrict__ wbb, const void* __restrict__ wgb,
    float* __restrict__ vcat, const int* __restrict__ flags)
{
  const int F = flags[1];
  const int j = blockIdx.x, lane = threadIdx.x;
  if (j >= 1028) { if (lane == 0) vcat[j] = 0.0f; return; }
  const int Kj = (j >= 512 && j < 1024) ? 512 : 899;
  float s = 0.0f;
  for (int o = lane; o < Kj; o += 64) {
    float w;
    if (j < 128) w = ldx(rkW, F, (long)j * 899 + o);
    else if (j < 256) w = ldx(wkW, F, (long)(j - 128) * 899 + o);
    else if (j < 384) w = ldx(erW, F, (long)(j - 256) * 899 + o);
    else if (j < 512) w = ldx(adW, F, (long)(j - 384) * 899 + o);
    else if (j < 1024) w = ldx(pW, F, (long)(j - 512) * 512 + o);
    else {
      const void* sp = (j == 1024) ? rbW : (j == 1025) ? rgW
                     : (j == 1026) ? wbW : wgW;
      w = ldx(sp, F, o);
    }
    s += w * ldx(bout, F, o);
  }
  #pragma unroll
  for (int off = 32; off > 0; off >>= 1) s += __shfl_down(s, off);
  if (lane == 0) {
    float b;
    if (j < 128) b = ldx(rkb, F, j);
    else if (j < 256) b = ldx(wkb, F, j - 128);
    else if (j < 384) b = ldx(erb, F, j - 256);
    else if (j < 512) b = ldx(adb, F, j - 384);
    else if (j < 1024) b = ldx(pb, F, j - 512);
    else if (j == 1024) b = ldx(rbb, F, 0);
    else if (j == 1025) b = ldx(rgb, F, 0);
    else if (j == 1026) b = ldx(wbb, F, 0);
    else b = ldx(wgb, F, 0);
    vcat[j] = s + b;
  }
}

extern "C" void kernel_launch(void* const* d_in, const int* in_sizes, int n_in,
                              void* d_out, int out_size, void* d_ws, size_t ws_size,
                              hipStream_t stream) {
  const void* x      = d_in[0];
  const void* memory = d_in[1];
  const void* Wih    = d_in[2];
  const void* Whh    = d_in[3];
  const void* bih    = d_in[4];
  const void* bhh    = d_in[5];
  const void* Wout   = d_in[6];
  const void* bout   = d_in[7];
  const void* rkW    = d_in[8];
  const void* rkb    = d_in[9];
  const void* rbW    = d_in[10];
  const void* rbb    = d_in[11];
  const void* rgW    = d_in[12];
  const void* rgb    = d_in[13];
  const void* wkW    = d_in[14];
  const void* wkb    = d_in[15];
  const void* wbW    = d_in[16];
  const void* wbb    = d_in[17];
  const void* wgW    = d_in[18];
  const void* wgb    = d_in[19];
  const void* erW    = d_in[20];
  const void* erb    = d_in[21];
  const void* adW    = d_in[22];
  const void* adb    = d_in[23];
  const void* pW     = d_in[24];
  const void* pb     = d_in[25];

  char* p = (char*)d_ws;
  auto alloc = [&](size_t bytes) -> char* {
    char* r = p; p += (bytes + 255) & ~(size_t)255; return r;
  };
  // big: [init] Wcat | WoutT  ->  [loop] Csim bf16 (8 MB) -> rv partials f32 (4 MB)
  char*           big    = alloc(256L * 16384 * 2);
  unsigned short* Wcat   = (unsigned short*)big;
  unsigned short* WoutT  = (unsigned short*)(big + 2359296);
  unsigned short* W_lstm = (unsigned short*)alloc(4096L * 1664 * 2);
  unsigned short* Wcomb  = (unsigned short*)alloc(1152L * 1024 * 2);
  float*          vcat   = (float*)alloc(1152L * 4);
  float*          bsum   = (float*)alloc(4096L * 4);
  unsigned short* x_bf   = (unsigned short*)alloc(32L * 128 * 512 * 2);
  unsigned short* ci_hA  = (unsigned short*)alloc(128L * 1664 * 2);
  unsigned short* ci_hB  = (unsigned short*)alloc(128L * 1664 * 2);
  float*          c      = (float*)alloc(128L * 1024 * 4);
  unsigned short* keys_n = (unsigned short*)alloc(256L * 128 * 2);
  unsigned short* EA     = (unsigned short*)alloc(256L * 128 * 2);
  float*          sc     = (float*)alloc(4L * 128 * 4);
  float*          rw     = (float*)alloc(128L * 16384 * 4);
  unsigned short* ww_nat = (unsigned short*)alloc(128L * 16384 * 2);
  float*          mem    = (float*)alloc(16384L * 128 * 4);
  unsigned short* memn   = (unsigned short*)alloc(16384L * 128 * 2);
  unsigned short* mem_bf = (unsigned short*)alloc(16384L * 128 * 2);
  int*            flags  = (int*)alloc(256);

  probe_dtype<<<1, 64, 0, stream>>>((const unsigned int*)Whh, flags);
  probe_layout<<<1, 64, 0, stream>>>(flags);
  init_pack<<<8192, 256, 0, stream>>>(x, Wih, Whh, bih, bhh, rkW, wkW, erW, adW,
                                      pW, rbW, rgW, wbW, wgW, W_lstm, bsum, x_bf,
                                      Wcat, ci_hA, c, rw, flags);
  init_mem<<<256, 256, 0, stream>>>(memory, mem, memn, mem_bf, flags);
  transpose_wout<<<dim3(16, 15, 1), 256, 0, stream>>>(Wout, WoutT, flags);
  init_vcat<<<1152, 64, 0, stream>>>(rkW, wkW, erW, adW, pW, rbW, rgW, wbW, wgW,
                                     bout, rkb, wkb, erb, adb, pb, rbb, rgb,
                                     wbb, wgb, vcat, flags);
  // Wcomb[1152,1024] = Wcat[1152,960] @ WoutT[1024,960]^T (bf16)
  gemm_pipe<128, 64, 2, 0, 0><<<dim3(9, 16, 1), 256, 0, stream>>>(
      Wcat, 960, WoutT, 960, 960, 1152, 1024, nullptr, 1024, Wcomb, flags);

  unsigned short* bufs[2] = {ci_hA, ci_hB};
  for (int t = 0; t < 32; ++t) {
    unsigned short* cur = bufs[t & 1];
    unsigned short* nxt = bufs[(t + 1) & 1];
    // gates GEMM + fused LSTM; writes h + xt(t+1) into nxt
    gemm_gates<<<dim3(2, 64, 1), 256, 0, stream>>>(
        cur, W_lstm, bsum, c, nxt, x_bf, t, flags);
    // heads: keys_n, EA (interleaved), sc, d_out
    gemm_heads<<<dim3(9, 2, 1), 256, 0, stream>>>(
        Wcomb, nxt + 640, 1664, vcat, keys_n, EA, sc, d_out, t, flags);
    // Csim[256,16384] = keys_n @ memn^T -> big (bf16)
    gemm_pipe<128, 64, 2, 0, 0><<<dim3(2, 256, 1), 256, 0, stream>>>(
        keys_n, 128, memn, 128, 128, 256, 16384, nullptr, 16384,
        (unsigned short*)big, flags);
    softmax1<<<256, 256, 0, stream>>>((const unsigned short*)big, sc, rw, ww_nat);
    // er/ad GEMM + memory update fused
    write_mem<<<256, 256, 0, stream>>>(ww_nat, EA, mem, memn, mem_bf, flags);
    // rv partials: rw(fp32)[128,16384] @ mem_bf[16384,128] (BT), split-K 64
    gemm_pipe<128, 64, 3, 1, 1><<<dim3(1, 2, 64), 256, 0, stream>>>(
        rw, 16384, mem_bf, 128, 256, 128, 128, (float*)big, 128, nullptr, flags);
    rv_reduce<<<64, 256, 0, stream>>>((const float*)big, nxt);
  }
}